// Round 3
// baseline (895.331 us; speedup 1.0000x reference)
//
#include <hip/hip_runtime.h>
#include <cmath>

static constexpr int B   = 256;
static constexpr int S   = 128;
static constexpr int ENC = 512;
static constexpr int DEC = 512;
static constexpr int EMB = 256;
static constexpr int V   = 32000;
static constexpr int KX  = EMB + ENC;        // 768  (GRU input concat [emb, weighted])
static constexpr int KF  = DEC + ENC + EMB;  // 1280 (fc input concat [h_new, weighted, emb])
static constexpr int G3  = 3 * DEC;          // 1536

__device__ __forceinline__ float sigmoidf(float xv) { return 1.0f / (1.0f + expf(-xv)); }

// ------------------------------------------------------------------
// Generic f32 tiled GEMM: C[M,N] = A[M,K] * B (+ bias)
// TRANSB=0: Bm is [K,N] row-major (ldb = row stride)
// TRANSB=1: Bm is [N,K] row-major (ldb = row stride)  -> C = A * Bm^T
// 64x64 block tile, 256 threads, 4x4 micro-tile, K-step 16.
// Requires M%64==0, N%64==0, K%16==0 (all shapes here satisfy this).
// ------------------------------------------------------------------
template<int TRANSB, int BIAS>
__global__ __launch_bounds__(256) void gemm_f32(
    const float* __restrict__ A, const float* __restrict__ Bm,
    const float* __restrict__ bias, float* __restrict__ C,
    int M, int N, int K, int lda, int ldb, int ldc)
{
    __shared__ float As[16][68];   // [k][m], stride 68 (272B = 17*16B, float4-aligned)
    __shared__ float Bs[16][68];   // [k][n]
    const int tid  = threadIdx.x;
    const int row0 = blockIdx.y * 64;
    const int col0 = blockIdx.x * 64;
    const int tx = tid & 15, ty = tid >> 4;

    float acc[4][4] = {};
    for (int k0 = 0; k0 < K; k0 += 16) {
        {   // A tile 64x16 -> As[k][m] (transposed store)
            const int m  = tid >> 2;
            const int kk = (tid & 3) << 2;
            const float4 a4 = *reinterpret_cast<const float4*>(
                &A[(size_t)(row0 + m) * lda + k0 + kk]);
            As[kk + 0][m] = a4.x; As[kk + 1][m] = a4.y;
            As[kk + 2][m] = a4.z; As[kk + 3][m] = a4.w;
        }
        if (TRANSB) {
            const int n  = tid >> 2;
            const int kk = (tid & 3) << 2;
            const float4 b4 = *reinterpret_cast<const float4*>(
                &Bm[(size_t)(col0 + n) * ldb + k0 + kk]);
            Bs[kk + 0][n] = b4.x; Bs[kk + 1][n] = b4.y;
            Bs[kk + 2][n] = b4.z; Bs[kk + 3][n] = b4.w;
        } else {
            const int kk = tid >> 4;
            const int n  = (tid & 15) << 2;
            *reinterpret_cast<float4*>(&Bs[kk][n]) =
                *reinterpret_cast<const float4*>(&Bm[(size_t)(k0 + kk) * ldb + col0 + n]);
        }
        __syncthreads();
        #pragma unroll
        for (int k = 0; k < 16; ++k) {
            float a4[4], b4[4];
            *reinterpret_cast<float4*>(a4) = *reinterpret_cast<const float4*>(&As[k][ty << 2]);
            *reinterpret_cast<float4*>(b4) = *reinterpret_cast<const float4*>(&Bs[k][tx << 2]);
            #pragma unroll
            for (int i = 0; i < 4; ++i)
                #pragma unroll
                for (int j = 0; j < 4; ++j)
                    acc[i][j] = fmaf(a4[i], b4[j], acc[i][j]);
        }
        __syncthreads();
    }
    #pragma unroll
    for (int i = 0; i < 4; ++i) {
        const int r = row0 + (ty << 2) + i;
        #pragma unroll
        for (int j = 0; j < 4; ++j) {
            const int c = col0 + (tx << 2) + j;
            float outv = acc[i][j];
            if (BIAS) outv += bias[c];
            C[(size_t)r * ldc + c] = outv;
        }
    }
}

// ------------------------------------------------------------------
// energy/scores: for row r = s*B+b of enc (treated as [S*B, ENC]):
//   t[c]      = sum_k enc[r][k] * attn_W[DEC + k][c]        (GEMM part)
//   partial   = sum_c v[c] * tanh(t[c] + hWb[b][c])          (epilogue)
//   scores[r] = sum over all 8 column-blocks (atomicAdd)
// hWb already contains h @ attn_W[0:DEC] + attn_b.
// ------------------------------------------------------------------
__global__ __launch_bounds__(256) void energy_scores(
    const float* __restrict__ enc, const float* __restrict__ Bm,
    const float* __restrict__ hWb, const float* __restrict__ vvec,
    float* __restrict__ scores)
{
    __shared__ float As[16][68];
    __shared__ float Bs[16][68];
    const int tid  = threadIdx.x;
    const int row0 = blockIdx.y * 64;
    const int col0 = blockIdx.x * 64;
    const int tx = tid & 15, ty = tid >> 4;

    float acc[4][4] = {};
    for (int k0 = 0; k0 < ENC; k0 += 16) {
        {
            const int m  = tid >> 2;
            const int kk = (tid & 3) << 2;
            const float4 a4 = *reinterpret_cast<const float4*>(
                &enc[(size_t)(row0 + m) * ENC + k0 + kk]);
            As[kk + 0][m] = a4.x; As[kk + 1][m] = a4.y;
            As[kk + 2][m] = a4.z; As[kk + 3][m] = a4.w;
        }
        {
            const int kk = tid >> 4;
            const int n  = (tid & 15) << 2;
            *reinterpret_cast<float4*>(&Bs[kk][n]) =
                *reinterpret_cast<const float4*>(&Bm[(size_t)(k0 + kk) * DEC + col0 + n]);
        }
        __syncthreads();
        #pragma unroll
        for (int k = 0; k < 16; ++k) {
            float a4[4], b4[4];
            *reinterpret_cast<float4*>(a4) = *reinterpret_cast<const float4*>(&As[k][ty << 2]);
            *reinterpret_cast<float4*>(b4) = *reinterpret_cast<const float4*>(&Bs[k][tx << 2]);
            #pragma unroll
            for (int i = 0; i < 4; ++i)
                #pragma unroll
                for (int j = 0; j < 4; ++j)
                    acc[i][j] = fmaf(a4[i], b4[j], acc[i][j]);
        }
        __syncthreads();
    }
    // epilogue: tanh + v-dot, reduce across the 16 lanes that share a row
    #pragma unroll
    for (int i = 0; i < 4; ++i) {
        const int r = row0 + (ty << 2) + i;
        const int b = r & (B - 1);   // r = s*B + b, B=256
        float p = 0.0f;
        #pragma unroll
        for (int j = 0; j < 4; ++j) {
            const int c = col0 + (tx << 2) + j;
            p += vvec[c] * tanhf(acc[i][j] + hWb[(size_t)b * DEC + c]);
        }
        p += __shfl_xor(p, 8, 64);
        p += __shfl_xor(p, 4, 64);
        p += __shfl_xor(p, 2, 64);
        p += __shfl_xor(p, 1, 64);
        if (tx == 0) atomicAdd(&scores[r], p);
    }
}

// ------------------------------------------------------------------
// per-b softmax over s (scores laid out [s][b]) + weighted sum of enc
// writes weighted into xcat[:, DEC:DEC+ENC] and x[:, EMB:EMB+ENC]
// ------------------------------------------------------------------
__global__ __launch_bounds__(256) void softmax_weighted(
    const float* __restrict__ scores, const float* __restrict__ enc,
    float* __restrict__ xcat, float* __restrict__ x)
{
    const int b   = blockIdx.x;
    const int tid = threadIdx.x;
    __shared__ float sa[S];
    __shared__ float red[128];

    const float sc = (tid < S) ? scores[(size_t)tid * B + b] : -1e30f;
    if (tid < 128) red[tid] = sc;
    __syncthreads();
    for (int off = 64; off >= 1; off >>= 1) {
        if (tid < off) red[tid] = fmaxf(red[tid], red[tid + off]);
        __syncthreads();
    }
    const float mx = red[0];
    __syncthreads();
    const float e = (tid < S) ? expf(sc - mx) : 0.0f;
    if (tid < 128) red[tid] = e;
    __syncthreads();
    for (int off = 64; off >= 1; off >>= 1) {
        if (tid < off) red[tid] += red[tid + off];
        __syncthreads();
    }
    const float inv = 1.0f / red[0];
    __syncthreads();
    if (tid < S) sa[tid] = e * inv;
    __syncthreads();

    float acc0 = 0.0f, acc1 = 0.0f;
    const int e0 = tid * 2;
    for (int s = 0; s < S; ++s) {
        const float w = sa[s];
        const float2 v2 = *reinterpret_cast<const float2*>(
            &enc[((size_t)s * B + b) * ENC + e0]);
        acc0 = fmaf(w, v2.x, acc0);
        acc1 = fmaf(w, v2.y, acc1);
    }
    const float2 wv = make_float2(acc0, acc1);
    *reinterpret_cast<float2*>(&xcat[(size_t)b * KF + DEC + e0]) = wv;
    *reinterpret_cast<float2*>(&x[(size_t)b * KX + EMB + e0])    = wv;
}

// emb gather -> xcat[:, DEC+ENC:] and x[:, 0:EMB]
__global__ void gather_emb(const int* __restrict__ tok, const float* __restrict__ table,
                           float* __restrict__ xcat, float* __restrict__ x)
{
    const int b = blockIdx.x, t = threadIdx.x;  // 64 threads
    const float4 v4 = *reinterpret_cast<const float4*>(
        &table[(size_t)tok[b] * EMB + t * 4]);
    *reinterpret_cast<float4*>(&xcat[(size_t)b * KF + DEC + ENC + t * 4]) = v4;
    *reinterpret_cast<float4*>(&x[(size_t)b * KX + t * 4]) = v4;
}

// GRU gates (PyTorch order r,z,n); writes h_new to xcat[:,0:DEC] and d_out tail
__global__ __launch_bounds__(256) void gru_gates(
    const float* __restrict__ gi, const float* __restrict__ gh,
    const float* __restrict__ h, float* __restrict__ xcat, float* __restrict__ h_out)
{
    const int idx = blockIdx.x * 256 + threadIdx.x;   // 0 .. B*DEC-1
    const int b = idx >> 9, d = idx & 511;
    const float* gib = gi + (size_t)b * G3;
    const float* ghb = gh + (size_t)b * G3;
    const float r  = sigmoidf(gib[d] + ghb[d]);
    const float z  = sigmoidf(gib[DEC + d] + ghb[DEC + d]);
    const float n  = tanhf(gib[2 * DEC + d] + r * ghb[2 * DEC + d]);
    const float hv = h[(size_t)b * DEC + d];
    const float hn = (1.0f - z) * n + z * hv;
    xcat[(size_t)b * KF + d] = hn;
    h_out[(size_t)b * DEC + d] = hn;
}

extern "C" void kernel_launch(void* const* d_in, const int* in_sizes, int n_in,
                              void* d_out, int out_size, void* d_ws, size_t ws_size,
                              hipStream_t stream)
{
    const int*   tok    = (const int*)d_in[0];
    const float* hidden = (const float*)d_in[1];   // [1,B,DEC] == [B,DEC]
    const float* enc    = (const float*)d_in[2];   // [S,B,ENC]
    const float* table  = (const float*)d_in[3];   // [V,EMB]
    const float* attn_W = (const float*)d_in[4];   // [DEC+ENC, DEC]
    const float* attn_b = (const float*)d_in[5];   // [DEC]
    const float* vvec   = (const float*)d_in[6];   // [DEC]
    const float* W_ih   = (const float*)d_in[7];   // [G3, KX]
    const float* W_hh   = (const float*)d_in[8];   // [G3, DEC]
    const float* b_ih   = (const float*)d_in[9];
    const float* b_hh   = (const float*)d_in[10];
    const float* fc_W   = (const float*)d_in[11];  // [V, KF]
    const float* fc_b   = (const float*)d_in[12];

    float* ws     = (float*)d_ws;
    float* hWb    = ws;                     // B*DEC      = 131072
    float* scores = hWb + B * DEC;          // S*B        =  32768
    float* x      = scores + S * B;         // B*KX       = 196608
    float* xcat   = x + B * KX;             // B*KF       = 327680
    float* gi     = xcat + B * KF;          // B*G3       = 393216
    float* gh     = gi + B * G3;            // B*G3       = 393216
    // total ~5.9 MB of f32 scratch

    float* pred  = (float*)d_out;               // [B,V]
    float* h_out = pred + (size_t)B * V;        // [B,DEC]

    // scores accumulated via atomicAdd -> zero first (ws is poisoned each call)
    hipMemsetAsync(scores, 0, (size_t)S * B * sizeof(float), stream);

    gather_emb<<<B, 64, 0, stream>>>(tok, table, xcat, x);

    // hWb = h @ attn_W[0:DEC,:] + attn_b   (cat order is [h_rep, enc])
    gemm_f32<0, 1><<<dim3(DEC / 64, B / 64), 256, 0, stream>>>(
        hidden, attn_W, attn_b, hWb, B, DEC, DEC, DEC, DEC, DEC);

    // scores[s*B+b] = v . tanh(hWb[b] + enc[s,b] @ attn_W[DEC:,:])
    energy_scores<<<dim3(DEC / 64, (S * B) / 64), 256, 0, stream>>>(
        enc, attn_W + (size_t)DEC * DEC, hWb, vvec, scores);

    softmax_weighted<<<B, 256, 0, stream>>>(scores, enc, xcat, x);

    // gi = x @ W_ih^T + b_ih ; gh = h @ W_hh^T + b_hh
    gemm_f32<1, 1><<<dim3(G3 / 64, B / 64), 256, 0, stream>>>(
        x, W_ih, b_ih, gi, B, G3, KX, KX, KX, G3);
    gemm_f32<1, 1><<<dim3(G3 / 64, B / 64), 256, 0, stream>>>(
        hidden, W_hh, b_hh, gh, B, G3, DEC, DEC, DEC, G3);

    gru_gates<<<(B * DEC) / 256, 256, 0, stream>>>(gi, gh, hidden, xcat, h_out);

    // pred = xcat @ fc_W^T + fc_b
    gemm_f32<1, 1><<<dim3(V / 64, B / 64), 256, 0, stream>>>(
        xcat, fc_W, fc_b, pred, B, V, KF, KF, KF, V);
}

// Round 4
// 526.927 us; speedup vs baseline: 1.6992x; 1.6992x over previous
//
#include <hip/hip_runtime.h>
#include <cmath>

static constexpr int B   = 256;
static constexpr int S   = 128;
static constexpr int ENC = 512;
static constexpr int DEC = 512;
static constexpr int EMB = 256;
static constexpr int V   = 32000;
static constexpr int KX  = EMB + ENC;        // 768
static constexpr int KF  = DEC + ENC + EMB;  // 1280
static constexpr int G3  = 3 * DEC;          // 1536

typedef __attribute__((ext_vector_type(8))) short short8v;
typedef __attribute__((ext_vector_type(4))) float f32x4;

__device__ __forceinline__ float sigmoidf(float xv) { return 1.0f / (1.0f + expf(-xv)); }

// f32 -> bf16 round-to-nearest-even (bit trick; no NaNs in this data)
__device__ __forceinline__ unsigned short f2bf(float f) {
    unsigned u = __float_as_uint(f);
    unsigned r = (u + 0x7fffu + ((u >> 16) & 1u)) >> 16;
    return (unsigned short)r;
}

// ------------------------------------------------------------------
// f32 tiled GEMM (kept for the small GEMMs: hW, gi, gh)
// ------------------------------------------------------------------
template<int TRANSB, int BIAS>
__global__ __launch_bounds__(256) void gemm_f32(
    const float* __restrict__ A, const float* __restrict__ Bm,
    const float* __restrict__ bias, float* __restrict__ C,
    int M, int N, int K, int lda, int ldb, int ldc)
{
    __shared__ float As[16][68];
    __shared__ float Bs[16][68];
    const int tid  = threadIdx.x;
    const int row0 = blockIdx.y * 64;
    const int col0 = blockIdx.x * 64;
    const int tx = tid & 15, ty = tid >> 4;

    float acc[4][4] = {};
    for (int k0 = 0; k0 < K; k0 += 16) {
        {
            const int m  = tid >> 2;
            const int kk = (tid & 3) << 2;
            const float4 a4 = *reinterpret_cast<const float4*>(
                &A[(size_t)(row0 + m) * lda + k0 + kk]);
            As[kk + 0][m] = a4.x; As[kk + 1][m] = a4.y;
            As[kk + 2][m] = a4.z; As[kk + 3][m] = a4.w;
        }
        if (TRANSB) {
            const int n  = tid >> 2;
            const int kk = (tid & 3) << 2;
            const float4 b4 = *reinterpret_cast<const float4*>(
                &Bm[(size_t)(col0 + n) * ldb + k0 + kk]);
            Bs[kk + 0][n] = b4.x; Bs[kk + 1][n] = b4.y;
            Bs[kk + 2][n] = b4.z; Bs[kk + 3][n] = b4.w;
        } else {
            const int kk = tid >> 4;
            const int n  = (tid & 15) << 2;
            *reinterpret_cast<float4*>(&Bs[kk][n]) =
                *reinterpret_cast<const float4*>(&Bm[(size_t)(k0 + kk) * ldb + col0 + n]);
        }
        __syncthreads();
        #pragma unroll
        for (int k = 0; k < 16; ++k) {
            float a4[4], b4[4];
            *reinterpret_cast<float4*>(a4) = *reinterpret_cast<const float4*>(&As[k][ty << 2]);
            *reinterpret_cast<float4*>(b4) = *reinterpret_cast<const float4*>(&Bs[k][tx << 2]);
            #pragma unroll
            for (int i = 0; i < 4; ++i)
                #pragma unroll
                for (int j = 0; j < 4; ++j)
                    acc[i][j] = fmaf(a4[i], b4[j], acc[i][j]);
        }
        __syncthreads();
    }
    #pragma unroll
    for (int i = 0; i < 4; ++i) {
        const int r = row0 + (ty << 2) + i;
        #pragma unroll
        for (int j = 0; j < 4; ++j) {
            const int c = col0 + (tx << 2) + j;
            float outv = acc[i][j];
            if (BIAS) outv += bias[c];
            C[(size_t)r * ldc + c] = outv;
        }
    }
}

// ------------------------------------------------------------------
// attn_W enc-half [k=512][n=512] f32 -> WeT [n=512][k=512] bf16
// 32x32 LDS-tiled transpose, coalesced both sides.
// ------------------------------------------------------------------
__global__ __launch_bounds__(256) void transpose_We(
    const float* __restrict__ attn_W, unsigned short* __restrict__ WeT)
{
    __shared__ float t[32][33];
    const int k0 = blockIdx.x * 32, n0 = blockIdx.y * 32;
    const int r = threadIdx.x >> 3, c4 = (threadIdx.x & 7) * 4;
    const float4 f = *reinterpret_cast<const float4*>(
        &attn_W[(size_t)(DEC + k0 + r) * DEC + n0 + c4]);
    t[r][c4] = f.x; t[r][c4 + 1] = f.y; t[r][c4 + 2] = f.z; t[r][c4 + 3] = f.w;
    __syncthreads();
    unsigned short o[4] = { f2bf(t[c4 + 0][r]), f2bf(t[c4 + 1][r]),
                            f2bf(t[c4 + 2][r]), f2bf(t[c4 + 3][r]) };
    *reinterpret_cast<uint2*>(&WeT[(size_t)(n0 + r) * 512 + k0 + c4]) =
        *reinterpret_cast<uint2*>(o);
}

// ------------------------------------------------------------------
// energy+scores, bf16 MFMA.
// C[32768, 512] = enc_bf16 @ WeT^T ; epilogue v.tanh(C + hWb) -> atomicAdd scores.
// BM=256, BN=256 (grid 128x2 logical), BK=32, 512 thr (8 waves 2Mx4N).
// LDS rows padded to 80B so 16-row ds_read_b128 is ~2-way (free).
// XCD swizzle: both nb of an mb land on same XCD -> enc read once from HBM.
// ------------------------------------------------------------------
__global__ __launch_bounds__(512) void energy_mfma(
    const float* __restrict__ enc, const unsigned short* __restrict__ WeT,
    const float* __restrict__ hWb, const float* __restrict__ vvec,
    float* __restrict__ scores)
{
    __shared__ unsigned short Ae[256 * 40];  // 20 KB, row stride 80B
    __shared__ unsigned short Be[256 * 40];  // 20 KB
    const int bid = blockIdx.x;                       // 256 blocks
    const int logical = (bid & 7) * 32 + (bid >> 3);  // chunk per XCD
    const int mb = logical >> 1, nb = logical & 1;
    const int tid = threadIdx.x, lane = tid & 63, wid = tid >> 6;
    const int wm = wid >> 2, wn = wid & 3;            // 2 x 4 waves
    const int l15 = lane & 15, lk = lane >> 4;

    f32x4 acc[8][4] = {};
    for (int k0 = 0; k0 < 512; k0 += 32) {
        #pragma unroll
        for (int j = 0; j < 2; ++j) {
            const int ci = tid + 512 * j;       // 1024 chunks of 8 elems
            const int row = ci >> 2, kc = ci & 3;
            const float* src = &enc[(size_t)(mb * 256 + row) * ENC + k0 + kc * 8];
            const float4 f0 = *reinterpret_cast<const float4*>(src);
            const float4 f1 = *reinterpret_cast<const float4*>(src + 4);
            short8v t;
            t[0] = (short)f2bf(f0.x); t[1] = (short)f2bf(f0.y);
            t[2] = (short)f2bf(f0.z); t[3] = (short)f2bf(f0.w);
            t[4] = (short)f2bf(f1.x); t[5] = (short)f2bf(f1.y);
            t[6] = (short)f2bf(f1.z); t[7] = (short)f2bf(f1.w);
            *reinterpret_cast<short8v*>(&Ae[row * 40 + kc * 8]) = t;
            *reinterpret_cast<short8v*>(&Be[row * 40 + kc * 8]) =
                *reinterpret_cast<const short8v*>(
                    &WeT[(size_t)(nb * 256 + row) * 512 + k0 + kc * 8]);
        }
        __syncthreads();
        short8v bfr[4];
        #pragma unroll
        for (int nf = 0; nf < 4; ++nf)
            bfr[nf] = *reinterpret_cast<const short8v*>(
                &Be[(wn * 64 + nf * 16 + l15) * 40 + lk * 8]);
        #pragma unroll
        for (int mf = 0; mf < 8; ++mf) {
            const short8v afr = *reinterpret_cast<const short8v*>(
                &Ae[(wm * 128 + mf * 16 + l15) * 40 + lk * 8]);
            #pragma unroll
            for (int nf = 0; nf < 4; ++nf)
                acc[mf][nf] = __builtin_amdgcn_mfma_f32_16x16x32_bf16(
                    afr, bfr[nf], acc[mf][nf], 0, 0, 0);
        }
        __syncthreads();
    }
    // epilogue: p = sum_c v[c]*tanh(acc + hWb[rl][c]); rl == local row (B=256)
    const int colbase = nb * 256 + wn * 64;
    #pragma unroll
    for (int mf = 0; mf < 8; ++mf) {
        const int rl0 = wm * 128 + mf * 16 + lk * 4;
        #pragma unroll
        for (int r = 0; r < 4; ++r) {
            const int rl = rl0 + r;
            float p = 0.0f;
            #pragma unroll
            for (int nf = 0; nf < 4; ++nf) {
                const int col = colbase + nf * 16 + l15;
                p += vvec[col] * tanhf(acc[mf][nf][r] + hWb[(size_t)rl * DEC + col]);
            }
            p += __shfl_xor(p, 1, 64);
            p += __shfl_xor(p, 2, 64);
            p += __shfl_xor(p, 4, 64);
            p += __shfl_xor(p, 8, 64);
            if (l15 == 0) atomicAdd(&scores[(size_t)mb * 256 + rl], p);
        }
    }
}

// ------------------------------------------------------------------
// fc: pred[256,32000] = xcat_bf16 @ fc_W^T + fc_b, bf16 MFMA.
// BM=256 (all M -> fc_W read exactly once), BN=64, BK=64, 256 thr (4 waves 2x2).
// fc_W converted f32->bf16 during reg-staging. A rows padded to 144B.
// ------------------------------------------------------------------
__global__ __launch_bounds__(256) void fc_mfma(
    const unsigned short* __restrict__ xcatb, const float* __restrict__ fcW,
    const float* __restrict__ fcb, float* __restrict__ pred)
{
    __shared__ unsigned short As[256 * 72];  // 36 KB, row stride 144B
    __shared__ unsigned short Bs[64 * 72];   // 9 KB
    const int n0 = blockIdx.x * 64;
    const int tid = threadIdx.x, lane = tid & 63, wid = tid >> 6;
    const int wm = wid & 1, wn = wid >> 1;   // 2 x 2 waves
    const int l15 = lane & 15, lk = lane >> 4;

    f32x4 acc[8][2] = {};
    for (int k0 = 0; k0 < KF; k0 += 64) {
        #pragma unroll
        for (int j = 0; j < 8; ++j) {        // A: 2048 chunks, bf16 direct
            const int ci = tid + 256 * j;
            const int row = ci >> 3, kc = ci & 7;
            *reinterpret_cast<short8v*>(&As[row * 72 + kc * 8]) =
                *reinterpret_cast<const short8v*>(
                    &xcatb[(size_t)row * KF + k0 + kc * 8]);
        }
        #pragma unroll
        for (int j = 0; j < 2; ++j) {        // B: 512 chunks, f32 -> bf16
            const int ci = tid + 256 * j;
            const int row = ci >> 3, kc = ci & 7;
            const float* src = &fcW[(size_t)(n0 + row) * KF + k0 + kc * 8];
            const float4 f0 = *reinterpret_cast<const float4*>(src);
            const float4 f1 = *reinterpret_cast<const float4*>(src + 4);
            short8v t;
            t[0] = (short)f2bf(f0.x); t[1] = (short)f2bf(f0.y);
            t[2] = (short)f2bf(f0.z); t[3] = (short)f2bf(f0.w);
            t[4] = (short)f2bf(f1.x); t[5] = (short)f2bf(f1.y);
            t[6] = (short)f2bf(f1.z); t[7] = (short)f2bf(f1.w);
            *reinterpret_cast<short8v*>(&Bs[row * 72 + kc * 8]) = t;
        }
        __syncthreads();
        #pragma unroll
        for (int kk = 0; kk < 2; ++kk) {
            short8v bfr[2];
            #pragma unroll
            for (int nf = 0; nf < 2; ++nf)
                bfr[nf] = *reinterpret_cast<const short8v*>(
                    &Bs[(wn * 32 + nf * 16 + l15) * 72 + kk * 32 + lk * 8]);
            #pragma unroll
            for (int mf = 0; mf < 8; ++mf) {
                const short8v afr = *reinterpret_cast<const short8v*>(
                    &As[(wm * 128 + mf * 16 + l15) * 72 + kk * 32 + lk * 8]);
                acc[mf][0] = __builtin_amdgcn_mfma_f32_16x16x32_bf16(
                    afr, bfr[0], acc[mf][0], 0, 0, 0);
                acc[mf][1] = __builtin_amdgcn_mfma_f32_16x16x32_bf16(
                    afr, bfr[1], acc[mf][1], 0, 0, 0);
            }
        }
        __syncthreads();
    }
    #pragma unroll
    for (int mf = 0; mf < 8; ++mf) {
        const int grow0 = wm * 128 + mf * 16 + lk * 4;
        #pragma unroll
        for (int nf = 0; nf < 2; ++nf) {
            const int gcol = n0 + wn * 32 + nf * 16 + l15;
            const float bias = fcb[gcol];
            #pragma unroll
            for (int r = 0; r < 4; ++r)
                pred[(size_t)(grow0 + r) * V + gcol] = acc[mf][nf][r] + bias;
        }
    }
}

// ------------------------------------------------------------------
// softmax over s per b + weighted sum of enc; writes x (f32) and xcatb (bf16)
// ------------------------------------------------------------------
__global__ __launch_bounds__(256) void softmax_weighted(
    const float* __restrict__ scores, const float* __restrict__ enc,
    unsigned short* __restrict__ xcatb, float* __restrict__ x)
{
    const int b   = blockIdx.x;
    const int tid = threadIdx.x;
    __shared__ float sa[S];
    __shared__ float red[128];

    const float sc = (tid < S) ? scores[(size_t)tid * B + b] : -1e30f;
    if (tid < 128) red[tid] = sc;
    __syncthreads();
    for (int off = 64; off >= 1; off >>= 1) {
        if (tid < off) red[tid] = fmaxf(red[tid], red[tid + off]);
        __syncthreads();
    }
    const float mx = red[0];
    __syncthreads();
    const float e = (tid < S) ? expf(sc - mx) : 0.0f;
    if (tid < 128) red[tid] = e;
    __syncthreads();
    for (int off = 64; off >= 1; off >>= 1) {
        if (tid < off) red[tid] += red[tid + off];
        __syncthreads();
    }
    const float inv = 1.0f / red[0];
    __syncthreads();
    if (tid < S) sa[tid] = e * inv;
    __syncthreads();

    float acc0 = 0.0f, acc1 = 0.0f;
    const int e0 = tid * 2;
    for (int s = 0; s < S; ++s) {
        const float w = sa[s];
        const float2 v2 = *reinterpret_cast<const float2*>(
            &enc[((size_t)s * B + b) * ENC + e0]);
        acc0 = fmaf(w, v2.x, acc0);
        acc1 = fmaf(w, v2.y, acc1);
    }
    *reinterpret_cast<float2*>(&x[(size_t)b * KX + EMB + e0]) = make_float2(acc0, acc1);
    unsigned short t2[2] = { f2bf(acc0), f2bf(acc1) };
    *reinterpret_cast<unsigned int*>(&xcatb[(size_t)b * KF + DEC + e0]) =
        *reinterpret_cast<unsigned int*>(t2);
}

// emb gather -> x[:,0:EMB] (f32) and xcatb[:,1024:1280] (bf16)
__global__ void gather_emb(const int* __restrict__ tok, const float* __restrict__ table,
                           unsigned short* __restrict__ xcatb, float* __restrict__ x)
{
    const int b = blockIdx.x, t = threadIdx.x;  // 64 threads
    const float4 v4 = *reinterpret_cast<const float4*>(
        &table[(size_t)tok[b] * EMB + t * 4]);
    *reinterpret_cast<float4*>(&x[(size_t)b * KX + t * 4]) = v4;
    unsigned short o[4] = { f2bf(v4.x), f2bf(v4.y), f2bf(v4.z), f2bf(v4.w) };
    *reinterpret_cast<uint2*>(&xcatb[(size_t)b * KF + DEC + ENC + t * 4]) =
        *reinterpret_cast<uint2*>(o);
}

// GRU gates; h_new -> xcatb[:,0:512] (bf16) and d_out tail (f32)
__global__ __launch_bounds__(256) void gru_gates(
    const float* __restrict__ gi, const float* __restrict__ gh,
    const float* __restrict__ h, unsigned short* __restrict__ xcatb,
    float* __restrict__ h_out)
{
    const int idx = blockIdx.x * 256 + threadIdx.x;
    const int b = idx >> 9, d = idx & 511;
    const float* gib = gi + (size_t)b * G3;
    const float* ghb = gh + (size_t)b * G3;
    const float r  = sigmoidf(gib[d] + ghb[d]);
    const float z  = sigmoidf(gib[DEC + d] + ghb[DEC + d]);
    const float n  = tanhf(gib[2 * DEC + d] + r * ghb[2 * DEC + d]);
    const float hv = h[(size_t)b * DEC + d];
    const float hn = (1.0f - z) * n + z * hv;
    xcatb[(size_t)b * KF + d] = f2bf(hn);
    h_out[(size_t)b * DEC + d] = hn;
}

extern "C" void kernel_launch(void* const* d_in, const int* in_sizes, int n_in,
                              void* d_out, int out_size, void* d_ws, size_t ws_size,
                              hipStream_t stream)
{
    const int*   tok    = (const int*)d_in[0];
    const float* hidden = (const float*)d_in[1];
    const float* enc    = (const float*)d_in[2];
    const float* table  = (const float*)d_in[3];
    const float* attn_W = (const float*)d_in[4];
    const float* attn_b = (const float*)d_in[5];
    const float* vvec   = (const float*)d_in[6];
    const float* W_ih   = (const float*)d_in[7];
    const float* W_hh   = (const float*)d_in[8];
    const float* b_ih   = (const float*)d_in[9];
    const float* b_hh   = (const float*)d_in[10];
    const float* fc_W   = (const float*)d_in[11];
    const float* fc_b   = (const float*)d_in[12];

    float* ws     = (float*)d_ws;
    float* hWb    = ws;                       // B*DEC   = 131072 f32
    float* scores = hWb + B * DEC;            // S*B     =  32768 f32
    float* x      = scores + S * B;           // B*KX    = 196608 f32
    float* gi     = x + B * KX;               // B*G3    = 393216 f32
    float* gh     = gi + B * G3;              // B*G3    = 393216 f32
    unsigned short* xcatb = (unsigned short*)(gh + B * G3);  // B*KF u16
    unsigned short* WeT   = xcatb + (size_t)B * KF;          // 512*512 u16
    // total ~5.8 MB

    float* pred  = (float*)d_out;
    float* h_out = pred + (size_t)B * V;

    hipMemsetAsync(scores, 0, (size_t)S * B * sizeof(float), stream);

    transpose_We<<<dim3(16, 16), 256, 0, stream>>>(attn_W, WeT);
    gather_emb<<<B, 64, 0, stream>>>(tok, table, xcatb, x);

    // hWb = h @ attn_W[0:DEC,:] + attn_b   (f32)
    gemm_f32<0, 1><<<dim3(DEC / 64, B / 64), 256, 0, stream>>>(
        hidden, attn_W, attn_b, hWb, B, DEC, DEC, DEC, DEC, DEC);

    energy_mfma<<<256, 512, 0, stream>>>(enc, WeT, hWb, vvec, scores);

    softmax_weighted<<<B, 256, 0, stream>>>(scores, enc, xcatb, x);

    gemm_f32<1, 1><<<dim3(G3 / 64, B / 64), 256, 0, stream>>>(
        x, W_ih, b_ih, gi, B, G3, KX, KX, KX, G3);
    gemm_f32<1, 1><<<dim3(G3 / 64, B / 64), 256, 0, stream>>>(
        hidden, W_hh, b_hh, gh, B, G3, DEC, DEC, DEC, G3);

    gru_gates<<<(B * DEC) / 256, 256, 0, stream>>>(gi, gh, hidden, xcatb, h_out);

    fc_mfma<<<V / 64, 256, 0, stream>>>(xcatb, fc_W, fc_b, pred);
}

// Round 9
// 490.625 us; speedup vs baseline: 1.8249x; 1.0740x over previous
//
#include <hip/hip_runtime.h>
#include <cmath>

static constexpr int B   = 256;
static constexpr int S   = 128;
static constexpr int ENC = 512;
static constexpr int DEC = 512;
static constexpr int EMB = 256;
static constexpr int V   = 32000;
static constexpr int KX  = EMB + ENC;        // 768
static constexpr int KF  = DEC + ENC + EMB;  // 1280
static constexpr int G3  = 3 * DEC;          // 1536

typedef __attribute__((ext_vector_type(8))) short short8v;
typedef __attribute__((ext_vector_type(4))) float f32x4;

__device__ __forceinline__ float sigmoidf(float xv) { return 1.0f / (1.0f + expf(-xv)); }

__device__ __forceinline__ unsigned short f2bf(float f) {
    unsigned u = __float_as_uint(f);
    unsigned r = (u + 0x7fffu + ((u >> 16) & 1u)) >> 16;
    return (unsigned short)r;
}
__device__ __forceinline__ float bf2f(unsigned short s) {
    return __uint_as_float(((unsigned)s) << 16);
}

// ------------------------------------------------------------------
// f32 tiled GEMM — used only for hWb (small, f32 accuracy kept on tanh arg)
// ------------------------------------------------------------------
template<int TRANSB, int BIAS>
__global__ __launch_bounds__(256) void gemm_f32(
    const float* __restrict__ A, const float* __restrict__ Bm,
    const float* __restrict__ bias, float* __restrict__ C,
    int M, int N, int K, int lda, int ldb, int ldc)
{
    __shared__ float As[16][68];
    __shared__ float Bs[16][68];
    const int tid  = threadIdx.x;
    const int row0 = blockIdx.y * 64;
    const int col0 = blockIdx.x * 64;
    const int tx = tid & 15, ty = tid >> 4;

    float acc[4][4] = {};
    for (int k0 = 0; k0 < K; k0 += 16) {
        {
            const int m  = tid >> 2;
            const int kk = (tid & 3) << 2;
            const float4 a4 = *reinterpret_cast<const float4*>(
                &A[(size_t)(row0 + m) * lda + k0 + kk]);
            As[kk + 0][m] = a4.x; As[kk + 1][m] = a4.y;
            As[kk + 2][m] = a4.z; As[kk + 3][m] = a4.w;
        }
        if (TRANSB) {
            const int n  = tid >> 2;
            const int kk = (tid & 3) << 2;
            const float4 b4 = *reinterpret_cast<const float4*>(
                &Bm[(size_t)(col0 + n) * ldb + k0 + kk]);
            Bs[kk + 0][n] = b4.x; Bs[kk + 1][n] = b4.y;
            Bs[kk + 2][n] = b4.z; Bs[kk + 3][n] = b4.w;
        } else {
            const int kk = tid >> 4;
            const int n  = (tid & 15) << 2;
            *reinterpret_cast<float4*>(&Bs[kk][n]) =
                *reinterpret_cast<const float4*>(&Bm[(size_t)(k0 + kk) * ldb + col0 + n]);
        }
        __syncthreads();
        #pragma unroll
        for (int k = 0; k < 16; ++k) {
            float a4[4], b4[4];
            *reinterpret_cast<float4*>(a4) = *reinterpret_cast<const float4*>(&As[k][ty << 2]);
            *reinterpret_cast<float4*>(b4) = *reinterpret_cast<const float4*>(&Bs[k][tx << 2]);
            #pragma unroll
            for (int i = 0; i < 4; ++i)
                #pragma unroll
                for (int j = 0; j < 4; ++j)
                    acc[i][j] = fmaf(a4[i], b4[j], acc[i][j]);
        }
        __syncthreads();
    }
    #pragma unroll
    for (int i = 0; i < 4; ++i) {
        const int r = row0 + (ty << 2) + i;
        #pragma unroll
        for (int j = 0; j < 4; ++j) {
            const int c = col0 + (tx << 2) + j;
            float outv = acc[i][j];
            if (BIAS) outv += bias[c];
            C[(size_t)r * ldc + c] = outv;
        }
    }
}

// enc f32 -> bf16, exact cover: 2048 blocks x 256 thr x 8 elems x 4 iters
__global__ __launch_bounds__(256) void conv_enc(
    const float* __restrict__ src, unsigned short* __restrict__ dst)
{
    size_t base = ((size_t)blockIdx.x * 256 + threadIdx.x) * 8;
    const size_t stride = (size_t)2048 * 256 * 8;
    #pragma unroll
    for (int it = 0; it < 4; ++it, base += stride) {
        const float4 f0 = *reinterpret_cast<const float4*>(&src[base]);
        const float4 f1 = *reinterpret_cast<const float4*>(&src[base + 4]);
        short8v t;
        t[0] = (short)f2bf(f0.x); t[1] = (short)f2bf(f0.y);
        t[2] = (short)f2bf(f0.z); t[3] = (short)f2bf(f0.w);
        t[4] = (short)f2bf(f1.x); t[5] = (short)f2bf(f1.y);
        t[6] = (short)f2bf(f1.z); t[7] = (short)f2bf(f1.w);
        *reinterpret_cast<short8v*>(&dst[base]) = t;
    }
}

// hidden f32 -> bf16 (131072 elems = 64 blocks x 256 thr x 8)
__global__ __launch_bounds__(256) void conv_h(
    const float* __restrict__ src, unsigned short* __restrict__ dst)
{
    const size_t base = ((size_t)blockIdx.x * 256 + threadIdx.x) * 8;
    const float4 f0 = *reinterpret_cast<const float4*>(&src[base]);
    const float4 f1 = *reinterpret_cast<const float4*>(&src[base + 4]);
    short8v t;
    t[0] = (short)f2bf(f0.x); t[1] = (short)f2bf(f0.y);
    t[2] = (short)f2bf(f0.z); t[3] = (short)f2bf(f0.w);
    t[4] = (short)f2bf(f1.x); t[5] = (short)f2bf(f1.y);
    t[6] = (short)f2bf(f1.z); t[7] = (short)f2bf(f1.w);
    *reinterpret_cast<short8v*>(&dst[base]) = t;
}

// attn_W enc-half [k=512][n=512] f32 -> WeT [n][k] bf16
__global__ __launch_bounds__(256) void transpose_We(
    const float* __restrict__ attn_W, unsigned short* __restrict__ WeT)
{
    __shared__ float t[32][33];
    const int k0 = blockIdx.x * 32, n0 = blockIdx.y * 32;
    const int r = threadIdx.x >> 3, c4 = (threadIdx.x & 7) * 4;
    const float4 f = *reinterpret_cast<const float4*>(
        &attn_W[(size_t)(DEC + k0 + r) * DEC + n0 + c4]);
    t[r][c4] = f.x; t[r][c4 + 1] = f.y; t[r][c4 + 2] = f.z; t[r][c4 + 3] = f.w;
    __syncthreads();
    unsigned short o[4] = { f2bf(t[c4 + 0][r]), f2bf(t[c4 + 1][r]),
                            f2bf(t[c4 + 2][r]), f2bf(t[c4 + 3][r]) };
    *reinterpret_cast<uint2*>(&WeT[(size_t)(n0 + r) * 512 + k0 + c4]) =
        *reinterpret_cast<uint2*>(o);
}

// ------------------------------------------------------------------
// energy v2: C[32768,512] = encb @ WeT^T; epilogue v.tanh(C+hWb) -> scores.
// BM=128, BN=256, BK=64, 512 thr (8 waves 2Mx4N), grid 512 (2 blocks/CU).
// LDS rows 72 shorts (144B): frag reads 2 lanes/bank (free).
// XCD swizzle pairs (mb, nb=0/1) on one XCD for enc L2 reuse.
// ------------------------------------------------------------------
__global__ __launch_bounds__(512, 4) void energy_mfma(
    const unsigned short* __restrict__ encb, const unsigned short* __restrict__ WeT,
    const float* __restrict__ hWb, const float* __restrict__ vvec,
    float* __restrict__ scores)
{
    __shared__ unsigned short Ae[128 * 72];  // 18 KB
    __shared__ unsigned short Be[256 * 72];  // 36 KB
    const int bid = blockIdx.x;                        // 512 blocks
    const int logical = (bid & 7) * 64 + (bid >> 3);   // bijective, 512%8==0
    const int mb = logical >> 1, nb = logical & 1;
    const int tid = threadIdx.x, lane = tid & 63, wid = tid >> 6;
    const int wm = wid >> 2, wn = wid & 3;             // 2 x 4 waves
    const int l15 = lane & 15, lk = lane >> 4;

    f32x4 acc[4][4] = {};
    for (int k0 = 0; k0 < 512; k0 += 64) {
        #pragma unroll
        for (int j = 0; j < 2; ++j) {          // A: 128 rows x 8 chunks
            const int ci = tid + 512 * j;
            const int row = ci >> 3, kc = ci & 7;
            *reinterpret_cast<short8v*>(&Ae[row * 72 + kc * 8]) =
                *reinterpret_cast<const short8v*>(
                    &encb[(size_t)(mb * 128 + row) * 512 + k0 + kc * 8]);
        }
        #pragma unroll
        for (int j = 0; j < 4; ++j) {          // B: 256 rows x 8 chunks
            const int ci = tid + 512 * j;
            const int row = ci >> 3, kc = ci & 7;
            *reinterpret_cast<short8v*>(&Be[row * 72 + kc * 8]) =
                *reinterpret_cast<const short8v*>(
                    &WeT[(size_t)(nb * 256 + row) * 512 + k0 + kc * 8]);
        }
        __syncthreads();
        #pragma unroll
        for (int kk = 0; kk < 2; ++kk) {
            short8v bfr[4];
            #pragma unroll
            for (int nf = 0; nf < 4; ++nf)
                bfr[nf] = *reinterpret_cast<const short8v*>(
                    &Be[(wn * 64 + nf * 16 + l15) * 72 + kk * 32 + lk * 8]);
            #pragma unroll
            for (int mf = 0; mf < 4; ++mf) {
                const short8v afr = *reinterpret_cast<const short8v*>(
                    &Ae[(wm * 64 + mf * 16 + l15) * 72 + kk * 32 + lk * 8]);
                #pragma unroll
                for (int nf = 0; nf < 4; ++nf)
                    acc[mf][nf] = __builtin_amdgcn_mfma_f32_16x16x32_bf16(
                        afr, bfr[nf], acc[mf][nf], 0, 0, 0);
            }
        }
        __syncthreads();
    }
    const int colbase = nb * 256 + wn * 64;
    #pragma unroll
    for (int mf = 0; mf < 4; ++mf) {
        #pragma unroll
        for (int r = 0; r < 4; ++r) {
            const int rl = wm * 64 + mf * 16 + lk * 4 + r;
            const int g  = mb * 128 + rl;       // global row = s*B + b
            const int b  = g & (B - 1);
            float p = 0.0f;
            #pragma unroll
            for (int nf = 0; nf < 4; ++nf) {
                const int col = colbase + nf * 16 + l15;
                p += vvec[col] * tanhf(acc[mf][nf][r] + hWb[(size_t)b * DEC + col]);
            }
            p += __shfl_xor(p, 1, 64);
            p += __shfl_xor(p, 2, 64);
            p += __shfl_xor(p, 4, 64);
            p += __shfl_xor(p, 8, 64);
            if (l15 == 0) atomicAdd(&scores[g], p);
        }
    }
}

// ------------------------------------------------------------------
// fc v2: pred[256,32000] = xcatb @ bf16(fc_W)^T + fc_b.
// BM=256, BN=128, BK=64, 512 thr (8 waves 2Mx4N), grid 250.
// ------------------------------------------------------------------
__global__ __launch_bounds__(512) void fc_mfma(
    const unsigned short* __restrict__ xcatb, const float* __restrict__ fcW,
    const float* __restrict__ fcb, float* __restrict__ pred)
{
    __shared__ unsigned short As[256 * 72];  // 36 KB
    __shared__ unsigned short Bs[128 * 72];  // 18 KB
    const int n0 = blockIdx.x * 128;
    const int tid = threadIdx.x, lane = tid & 63, wid = tid >> 6;
    const int wm = wid >> 2, wn = wid & 3;   // 2 x 4 waves: 128 rows x 32 cols
    const int l15 = lane & 15, lk = lane >> 4;

    f32x4 acc[8][2] = {};
    for (int k0 = 0; k0 < KF; k0 += 64) {
        #pragma unroll
        for (int j = 0; j < 4; ++j) {        // A: 256 rows x 8 chunks, bf16 copy
            const int ci = tid + 512 * j;
            const int row = ci >> 3, kc = ci & 7;
            *reinterpret_cast<short8v*>(&As[row * 72 + kc * 8]) =
                *reinterpret_cast<const short8v*>(
                    &xcatb[(size_t)row * KF + k0 + kc * 8]);
        }
        #pragma unroll
        for (int j = 0; j < 2; ++j) {        // B: 128 rows x 8 chunks, f32->bf16
            const int ci = tid + 512 * j;
            const int row = ci >> 3, kc = ci & 7;
            const float* src = &fcW[(size_t)(n0 + row) * KF + k0 + kc * 8];
            const float4 f0 = *reinterpret_cast<const float4*>(src);
            const float4 f1 = *reinterpret_cast<const float4*>(src + 4);
            short8v t;
            t[0] = (short)f2bf(f0.x); t[1] = (short)f2bf(f0.y);
            t[2] = (short)f2bf(f0.z); t[3] = (short)f2bf(f0.w);
            t[4] = (short)f2bf(f1.x); t[5] = (short)f2bf(f1.y);
            t[6] = (short)f2bf(f1.z); t[7] = (short)f2bf(f1.w);
            *reinterpret_cast<short8v*>(&Bs[row * 72 + kc * 8]) = t;
        }
        __syncthreads();
        #pragma unroll
        for (int kk = 0; kk < 2; ++kk) {
            short8v bfr[2];
            #pragma unroll
            for (int nf = 0; nf < 2; ++nf)
                bfr[nf] = *reinterpret_cast<const short8v*>(
                    &Bs[(wn * 32 + nf * 16 + l15) * 72 + kk * 32 + lk * 8]);
            #pragma unroll
            for (int mf = 0; mf < 8; ++mf) {
                const short8v afr = *reinterpret_cast<const short8v*>(
                    &As[(wm * 128 + mf * 16 + l15) * 72 + kk * 32 + lk * 8]);
                acc[mf][0] = __builtin_amdgcn_mfma_f32_16x16x32_bf16(
                    afr, bfr[0], acc[mf][0], 0, 0, 0);
                acc[mf][1] = __builtin_amdgcn_mfma_f32_16x16x32_bf16(
                    afr, bfr[1], acc[mf][1], 0, 0, 0);
            }
        }
        __syncthreads();
    }
    #pragma unroll
    for (int mf = 0; mf < 8; ++mf) {
        const int grow0 = wm * 128 + mf * 16 + lk * 4;
        #pragma unroll
        for (int nf = 0; nf < 2; ++nf) {
            const int gcol = n0 + wn * 32 + nf * 16 + l15;
            const float bias = fcb[gcol];
            #pragma unroll
            for (int r = 0; r < 4; ++r)
                pred[(size_t)(grow0 + r) * V + gcol] = acc[mf][nf][r] + bias;
        }
    }
}

// ------------------------------------------------------------------
// small bf16 GEMM for gi/gh: C[256,N] = Abf[256,K] @ bf16(Wf[N,K])^T + bias
// BM=256, BN=64, BK=64, 256 thr (4 waves 2Mx2N).
// ------------------------------------------------------------------
__global__ __launch_bounds__(256) void gemm_bf16_small(
    const unsigned short* __restrict__ Abf, const float* __restrict__ Wf,
    const float* __restrict__ bias, float* __restrict__ C, int K, int ldc)
{
    __shared__ unsigned short As[256 * 72];  // 36 KB
    __shared__ unsigned short Bs[64 * 72];   // 9 KB
    const int n0 = blockIdx.x * 64;
    const int tid = threadIdx.x, lane = tid & 63, wid = tid >> 6;
    const int wm = wid >> 1, wn = wid & 1;   // 2 x 2 waves: 128 rows x 32 cols
    const int l15 = lane & 15, lk = lane >> 4;

    f32x4 acc[8][2] = {};
    for (int k0 = 0; k0 < K; k0 += 64) {
        #pragma unroll
        for (int j = 0; j < 8; ++j) {        // A: 2048 chunks
            const int ci = tid + 256 * j;
            const int row = ci >> 3, kc = ci & 7;
            *reinterpret_cast<short8v*>(&As[row * 72 + kc * 8]) =
                *reinterpret_cast<const short8v*>(
                    &Abf[(size_t)row * K + k0 + kc * 8]);
        }
        #pragma unroll
        for (int j = 0; j < 2; ++j) {        // B: 512 chunks, f32->bf16
            const int ci = tid + 256 * j;
            const int row = ci >> 3, kc = ci & 7;
            const float* src = &Wf[(size_t)(n0 + row) * K + k0 + kc * 8];
            const float4 f0 = *reinterpret_cast<const float4*>(src);
            const float4 f1 = *reinterpret_cast<const float4*>(src + 4);
            short8v t;
            t[0] = (short)f2bf(f0.x); t[1] = (short)f2bf(f0.y);
            t[2] = (short)f2bf(f0.z); t[3] = (short)f2bf(f0.w);
            t[4] = (short)f2bf(f1.x); t[5] = (short)f2bf(f1.y);
            t[6] = (short)f2bf(f1.z); t[7] = (short)f2bf(f1.w);
            *reinterpret_cast<short8v*>(&Bs[row * 72 + kc * 8]) = t;
        }
        __syncthreads();
        #pragma unroll
        for (int kk = 0; kk < 2; ++kk) {
            short8v bfr[2];
            #pragma unroll
            for (int nf = 0; nf < 2; ++nf)
                bfr[nf] = *reinterpret_cast<const short8v*>(
                    &Bs[(wn * 32 + nf * 16 + l15) * 72 + kk * 32 + lk * 8]);
            #pragma unroll
            for (int mf = 0; mf < 8; ++mf) {
                const short8v afr = *reinterpret_cast<const short8v*>(
                    &As[(wm * 128 + mf * 16 + l15) * 72 + kk * 32 + lk * 8]);
                acc[mf][0] = __builtin_amdgcn_mfma_f32_16x16x32_bf16(
                    afr, bfr[0], acc[mf][0], 0, 0, 0);
                acc[mf][1] = __builtin_amdgcn_mfma_f32_16x16x32_bf16(
                    afr, bfr[1], acc[mf][1], 0, 0, 0);
            }
        }
        __syncthreads();
    }
    #pragma unroll
    for (int mf = 0; mf < 8; ++mf) {
        const int grow0 = wm * 128 + mf * 16 + lk * 4;
        #pragma unroll
        for (int nf = 0; nf < 2; ++nf) {
            const int gcol = n0 + wn * 32 + nf * 16 + l15;
            const float bv = bias[gcol];
            #pragma unroll
            for (int r = 0; r < 4; ++r)
                C[(size_t)(grow0 + r) * ldc + gcol] = acc[mf][nf][r] + bv;
        }
    }
}

// ------------------------------------------------------------------
// softmax over s per b + weighted sum (from encb bf16); writes weighted
// into xcatb[:,512:1024] and xb[:,256:768] (both bf16).
// ------------------------------------------------------------------
__global__ __launch_bounds__(256) void softmax_weighted(
    const float* __restrict__ scores, const unsigned short* __restrict__ encb,
    unsigned short* __restrict__ xcatb, unsigned short* __restrict__ xb)
{
    const int b   = blockIdx.x;
    const int tid = threadIdx.x;
    __shared__ float sa[S];
    __shared__ float red[128];

    const float sc = (tid < S) ? scores[(size_t)tid * B + b] : -1e30f;
    if (tid < 128) red[tid] = sc;
    __syncthreads();
    for (int off = 64; off >= 1; off >>= 1) {
        if (tid < off) red[tid] = fmaxf(red[tid], red[tid + off]);
        __syncthreads();
    }
    const float mx = red[0];
    __syncthreads();
    const float e = (tid < S) ? expf(sc - mx) : 0.0f;
    if (tid < 128) red[tid] = e;
    __syncthreads();
    for (int off = 64; off >= 1; off >>= 1) {
        if (tid < off) red[tid] += red[tid + off];
        __syncthreads();
    }
    const float inv = 1.0f / red[0];
    __syncthreads();
    if (tid < S) sa[tid] = e * inv;
    __syncthreads();

    float acc0 = 0.0f, acc1 = 0.0f;
    const int e0 = tid * 2;
    for (int s = 0; s < S; ++s) {
        const float w = sa[s];
        const unsigned u = *reinterpret_cast<const unsigned*>(
            &encb[((size_t)s * B + b) * ENC + e0]);
        acc0 = fmaf(w, bf2f((unsigned short)(u & 0xffffu)), acc0);
        acc1 = fmaf(w, bf2f((unsigned short)(u >> 16)), acc1);
    }
    unsigned short t2[2] = { f2bf(acc0), f2bf(acc1) };
    const unsigned packed = *reinterpret_cast<unsigned*>(t2);
    *reinterpret_cast<unsigned*>(&xcatb[(size_t)b * KF + DEC + e0]) = packed;
    *reinterpret_cast<unsigned*>(&xb[(size_t)b * KX + EMB + e0])    = packed;
}

// emb gather -> xb[:,0:256] and xcatb[:,1024:1280] (bf16)
__global__ void gather_emb(const int* __restrict__ tok, const float* __restrict__ table,
                           unsigned short* __restrict__ xcatb, unsigned short* __restrict__ xb)
{
    const int b = blockIdx.x, t = threadIdx.x;  // 64 threads
    const float4 v4 = *reinterpret_cast<const float4*>(
        &table[(size_t)tok[b] * EMB + t * 4]);
    unsigned short o[4] = { f2bf(v4.x), f2bf(v4.y), f2bf(v4.z), f2bf(v4.w) };
    const uint2 p = *reinterpret_cast<uint2*>(o);
    *reinterpret_cast<uint2*>(&xcatb[(size_t)b * KF + DEC + ENC + t * 4]) = p;
    *reinterpret_cast<uint2*>(&xb[(size_t)b * KX + t * 4]) = p;
}

// GRU gates; h_new -> xcatb[:,0:512] (bf16) and d_out tail (f32)
__global__ __launch_bounds__(256) void gru_gates(
    const float* __restrict__ gi, const float* __restrict__ gh,
    const float* __restrict__ h, unsigned short* __restrict__ xcatb,
    float* __restrict__ h_out)
{
    const int idx = blockIdx.x * 256 + threadIdx.x;
    const int b = idx >> 9, d = idx & 511;
    const float* gib = gi + (size_t)b * G3;
    const float* ghb = gh + (size_t)b * G3;
    const float r  = sigmoidf(gib[d] + ghb[d]);
    const float z  = sigmoidf(gib[DEC + d] + ghb[DEC + d]);
    const float n  = tanhf(gib[2 * DEC + d] + r * ghb[2 * DEC + d]);
    const float hv = h[(size_t)b * DEC + d];
    const float hn = (1.0f - z) * n + z * hv;
    xcatb[(size_t)b * KF + d] = f2bf(hn);
    h_out[(size_t)b * DEC + d] = hn;
}

extern "C" void kernel_launch(void* const* d_in, const int* in_sizes, int n_in,
                              void* d_out, int out_size, void* d_ws, size_t ws_size,
                              hipStream_t stream)
{
    const int*   tok    = (const int*)d_in[0];
    const float* hidden = (const float*)d_in[1];
    const float* enc    = (const float*)d_in[2];
    const float* table  = (const float*)d_in[3];
    const float* attn_W = (const float*)d_in[4];
    const float* attn_b = (const float*)d_in[5];
    const float* vvec   = (const float*)d_in[6];
    const float* W_ih   = (const float*)d_in[7];
    const float* W_hh   = (const float*)d_in[8];
    const float* b_ih   = (const float*)d_in[9];
    const float* b_hh   = (const float*)d_in[10];
    const float* fc_W   = (const float*)d_in[11];
    const float* fc_b   = (const float*)d_in[12];

    float* ws     = (float*)d_ws;
    float* hWb    = ws;                       // 131072 f32
    float* scores = hWb + B * DEC;            //  32768 f32
    float* gi     = scores + S * B;           // 393216 f32
    float* gh     = gi + B * G3;              // 393216 f32
    unsigned short* xcatb = (unsigned short*)(gh + B * G3);     // B*KF
    unsigned short* WeT   = xcatb + (size_t)B * KF;             // 512*512
    unsigned short* xb    = WeT + (size_t)512 * 512;            // B*KX
    unsigned short* hb    = xb + (size_t)B * KX;                // B*DEC
    unsigned short* encb  = hb + (size_t)B * DEC;               // 32768*512 (16B-aligned: all prior u16 counts even)
    // total ~39 MB

    float* pred  = (float*)d_out;
    float* h_out = pred + (size_t)B * V;

    hipMemsetAsync(scores, 0, (size_t)S * B * sizeof(float), stream);

    conv_enc<<<2048, 256, 0, stream>>>(enc, encb);
    conv_h<<<64, 256, 0, stream>>>(hidden, hb);
    transpose_We<<<dim3(16, 16), 256, 0, stream>>>(attn_W, WeT);
    gather_emb<<<B, 64, 0, stream>>>(tok, table, xcatb, xb);

    // hWb = h @ attn_W[0:DEC,:] + attn_b   (f32 for tanh-arg accuracy)
    gemm_f32<0, 1><<<dim3(DEC / 64, B / 64), 256, 0, stream>>>(
        hidden, attn_W, attn_b, hWb, B, DEC, DEC, DEC, DEC, DEC);

    energy_mfma<<<512, 512, 0, stream>>>(encb, WeT, hWb, vvec, scores);

    softmax_weighted<<<B, 256, 0, stream>>>(scores, encb, xcatb, xb);

    gemm_bf16_small<<<G3 / 64, 256, 0, stream>>>(xb, W_ih, b_ih, gi, KX, G3);
    gemm_bf16_small<<<G3 / 64, 256, 0, stream>>>(hb, W_hh, b_hh, gh, DEC, G3);

    gru_gates<<<(B * DEC) / 256, 256, 0, stream>>>(gi, gh, hidden, xcatb, h_out);

    fc_mfma<<<V / 128, 512, 0, stream>>>(xcatb, fc_W, fc_b, pred);
}

// Round 10
// 477.346 us; speedup vs baseline: 1.8756x; 1.0278x over previous
//
#include <hip/hip_runtime.h>
#include <cmath>

static constexpr int B   = 256;
static constexpr int S   = 128;
static constexpr int ENC = 512;
static constexpr int DEC = 512;
static constexpr int EMB = 256;
static constexpr int V   = 32000;
static constexpr int KX  = EMB + ENC;        // 768
static constexpr int KF  = DEC + ENC + EMB;  // 1280
static constexpr int G3  = 3 * DEC;          // 1536

typedef __attribute__((ext_vector_type(8))) short short8v;
typedef __attribute__((ext_vector_type(4))) float f32x4;

__device__ __forceinline__ float sigmoidf(float xv) { return 1.0f / (1.0f + expf(-xv)); }

__device__ __forceinline__ unsigned short f2bf(float f) {
    unsigned u = __float_as_uint(f);
    unsigned r = (u + 0x7fffu + ((u >> 16) & 1u)) >> 16;
    return (unsigned short)r;
}
__device__ __forceinline__ float bf2f(unsigned short s) {
    return __uint_as_float(((unsigned)s) << 16);
}

// ------------------------------------------------------------------
// f32 tiled GEMM — used only for hWb (small, f32 accuracy kept on tanh arg)
// ------------------------------------------------------------------
template<int TRANSB, int BIAS>
__global__ __launch_bounds__(256) void gemm_f32(
    const float* __restrict__ A, const float* __restrict__ Bm,
    const float* __restrict__ bias, float* __restrict__ C,
    int M, int N, int K, int lda, int ldb, int ldc)
{
    __shared__ float As[16][68];
    __shared__ float Bs[16][68];
    const int tid  = threadIdx.x;
    const int row0 = blockIdx.y * 64;
    const int col0 = blockIdx.x * 64;
    const int tx = tid & 15, ty = tid >> 4;

    float acc[4][4] = {};
    for (int k0 = 0; k0 < K; k0 += 16) {
        {
            const int m  = tid >> 2;
            const int kk = (tid & 3) << 2;
            const float4 a4 = *reinterpret_cast<const float4*>(
                &A[(size_t)(row0 + m) * lda + k0 + kk]);
            As[kk + 0][m] = a4.x; As[kk + 1][m] = a4.y;
            As[kk + 2][m] = a4.z; As[kk + 3][m] = a4.w;
        }
        if (TRANSB) {
            const int n  = tid >> 2;
            const int kk = (tid & 3) << 2;
            const float4 b4 = *reinterpret_cast<const float4*>(
                &Bm[(size_t)(col0 + n) * ldb + k0 + kk]);
            Bs[kk + 0][n] = b4.x; Bs[kk + 1][n] = b4.y;
            Bs[kk + 2][n] = b4.z; Bs[kk + 3][n] = b4.w;
        } else {
            const int kk = tid >> 4;
            const int n  = (tid & 15) << 2;
            *reinterpret_cast<float4*>(&Bs[kk][n]) =
                *reinterpret_cast<const float4*>(&Bm[(size_t)(k0 + kk) * ldb + col0 + n]);
        }
        __syncthreads();
        #pragma unroll
        for (int k = 0; k < 16; ++k) {
            float a4[4], b4[4];
            *reinterpret_cast<float4*>(a4) = *reinterpret_cast<const float4*>(&As[k][ty << 2]);
            *reinterpret_cast<float4*>(b4) = *reinterpret_cast<const float4*>(&Bs[k][tx << 2]);
            #pragma unroll
            for (int i = 0; i < 4; ++i)
                #pragma unroll
                for (int j = 0; j < 4; ++j)
                    acc[i][j] = fmaf(a4[i], b4[j], acc[i][j]);
        }
        __syncthreads();
    }
    #pragma unroll
    for (int i = 0; i < 4; ++i) {
        const int r = row0 + (ty << 2) + i;
        #pragma unroll
        for (int j = 0; j < 4; ++j) {
            const int c = col0 + (tx << 2) + j;
            float outv = acc[i][j];
            if (BIAS) outv += bias[c];
            C[(size_t)r * ldc + c] = outv;
        }
    }
}

// enc f32 -> bf16, exact cover: 2048 blocks x 256 thr x 8 elems x 4 iters
__global__ __launch_bounds__(256) void conv_enc(
    const float* __restrict__ src, unsigned short* __restrict__ dst)
{
    size_t base = ((size_t)blockIdx.x * 256 + threadIdx.x) * 8;
    const size_t stride = (size_t)2048 * 256 * 8;
    #pragma unroll
    for (int it = 0; it < 4; ++it, base += stride) {
        const float4 f0 = *reinterpret_cast<const float4*>(&src[base]);
        const float4 f1 = *reinterpret_cast<const float4*>(&src[base + 4]);
        short8v t;
        t[0] = (short)f2bf(f0.x); t[1] = (short)f2bf(f0.y);
        t[2] = (short)f2bf(f0.z); t[3] = (short)f2bf(f0.w);
        t[4] = (short)f2bf(f1.x); t[5] = (short)f2bf(f1.y);
        t[6] = (short)f2bf(f1.z); t[7] = (short)f2bf(f1.w);
        *reinterpret_cast<short8v*>(&dst[base]) = t;
    }
}

// hidden f32 -> bf16 (131072 elems = 64 blocks x 256 thr x 8)
__global__ __launch_bounds__(256) void conv_h(
    const float* __restrict__ src, unsigned short* __restrict__ dst)
{
    const size_t base = ((size_t)blockIdx.x * 256 + threadIdx.x) * 8;
    const float4 f0 = *reinterpret_cast<const float4*>(&src[base]);
    const float4 f1 = *reinterpret_cast<const float4*>(&src[base + 4]);
    short8v t;
    t[0] = (short)f2bf(f0.x); t[1] = (short)f2bf(f0.y);
    t[2] = (short)f2bf(f0.z); t[3] = (short)f2bf(f0.w);
    t[4] = (short)f2bf(f1.x); t[5] = (short)f2bf(f1.y);
    t[6] = (short)f2bf(f1.z); t[7] = (short)f2bf(f1.w);
    *reinterpret_cast<short8v*>(&dst[base]) = t;
}

// attn_W enc-half [k=512][n=512] f32 -> WeT [n][k] bf16
__global__ __launch_bounds__(256) void transpose_We(
    const float* __restrict__ attn_W, unsigned short* __restrict__ WeT)
{
    __shared__ float t[32][33];
    const int k0 = blockIdx.x * 32, n0 = blockIdx.y * 32;
    const int r = threadIdx.x >> 3, c4 = (threadIdx.x & 7) * 4;
    const float4 f = *reinterpret_cast<const float4*>(
        &attn_W[(size_t)(DEC + k0 + r) * DEC + n0 + c4]);
    t[r][c4] = f.x; t[r][c4 + 1] = f.y; t[r][c4 + 2] = f.z; t[r][c4 + 3] = f.w;
    __syncthreads();
    unsigned short o[4] = { f2bf(t[c4 + 0][r]), f2bf(t[c4 + 1][r]),
                            f2bf(t[c4 + 2][r]), f2bf(t[c4 + 3][r]) };
    *reinterpret_cast<uint2*>(&WeT[(size_t)(n0 + r) * 512 + k0 + c4]) =
        *reinterpret_cast<uint2*>(o);
}

// ------------------------------------------------------------------
// energy v2: C[32768,512] = encb @ WeT^T; epilogue v.tanh(C+hWb) -> scores.
// BM=128, BN=256, BK=64, 512 thr (8 waves 2Mx4N), grid 512 (2 blocks/CU).
// ------------------------------------------------------------------
__global__ __launch_bounds__(512, 4) void energy_mfma(
    const unsigned short* __restrict__ encb, const unsigned short* __restrict__ WeT,
    const float* __restrict__ hWb, const float* __restrict__ vvec,
    float* __restrict__ scores)
{
    __shared__ unsigned short Ae[128 * 72];  // 18 KB
    __shared__ unsigned short Be[256 * 72];  // 36 KB
    const int bid = blockIdx.x;                        // 512 blocks
    const int logical = (bid & 7) * 64 + (bid >> 3);   // bijective, 512%8==0
    const int mb = logical >> 1, nb = logical & 1;
    const int tid = threadIdx.x, lane = tid & 63, wid = tid >> 6;
    const int wm = wid >> 2, wn = wid & 3;             // 2 x 4 waves
    const int l15 = lane & 15, lk = lane >> 4;

    f32x4 acc[4][4] = {};
    for (int k0 = 0; k0 < 512; k0 += 64) {
        #pragma unroll
        for (int j = 0; j < 2; ++j) {          // A: 128 rows x 8 chunks
            const int ci = tid + 512 * j;
            const int row = ci >> 3, kc = ci & 7;
            *reinterpret_cast<short8v*>(&Ae[row * 72 + kc * 8]) =
                *reinterpret_cast<const short8v*>(
                    &encb[(size_t)(mb * 128 + row) * 512 + k0 + kc * 8]);
        }
        #pragma unroll
        for (int j = 0; j < 4; ++j) {          // B: 256 rows x 8 chunks
            const int ci = tid + 512 * j;
            const int row = ci >> 3, kc = ci & 7;
            *reinterpret_cast<short8v*>(&Be[row * 72 + kc * 8]) =
                *reinterpret_cast<const short8v*>(
                    &WeT[(size_t)(nb * 256 + row) * 512 + k0 + kc * 8]);
        }
        __syncthreads();
        #pragma unroll
        for (int kk = 0; kk < 2; ++kk) {
            short8v bfr[4];
            #pragma unroll
            for (int nf = 0; nf < 4; ++nf)
                bfr[nf] = *reinterpret_cast<const short8v*>(
                    &Be[(wn * 64 + nf * 16 + l15) * 72 + kk * 32 + lk * 8]);
            #pragma unroll
            for (int mf = 0; mf < 4; ++mf) {
                const short8v afr = *reinterpret_cast<const short8v*>(
                    &Ae[(wm * 64 + mf * 16 + l15) * 72 + kk * 32 + lk * 8]);
                #pragma unroll
                for (int nf = 0; nf < 4; ++nf)
                    acc[mf][nf] = __builtin_amdgcn_mfma_f32_16x16x32_bf16(
                        afr, bfr[nf], acc[mf][nf], 0, 0, 0);
            }
        }
        __syncthreads();
    }
    const int colbase = nb * 256 + wn * 64;
    #pragma unroll
    for (int mf = 0; mf < 4; ++mf) {
        #pragma unroll
        for (int r = 0; r < 4; ++r) {
            const int rl = wm * 64 + mf * 16 + lk * 4 + r;
            const int g  = mb * 128 + rl;       // global row = s*B + b
            const int b  = g & (B - 1);
            float p = 0.0f;
            #pragma unroll
            for (int nf = 0; nf < 4; ++nf) {
                const int col = colbase + nf * 16 + l15;
                p += vvec[col] * tanhf(acc[mf][nf][r] + hWb[(size_t)b * DEC + col]);
            }
            p += __shfl_xor(p, 1, 64);
            p += __shfl_xor(p, 2, 64);
            p += __shfl_xor(p, 4, 64);
            p += __shfl_xor(p, 8, 64);
            if (l15 == 0) atomicAdd(&scores[g], p);
        }
    }
}

// ------------------------------------------------------------------
// fc v3: pred[256,32000] = xcatb @ bf16(fc_W)^T + fc_b.
// BM=256 (fc_W read once), BN=64, BK=64, 512 thr (8 waves 4Mx2N), grid 500.
// LDS 45KB -> 2 blocks/CU (4 waves/SIMD): block-level overlap of HBM
// staging latency with the co-resident block's MFMA phase (round-9 showed
// 1 block/CU is latency-bound: MfmaUtil 8%, VALUBusy 6%, HBM 15%).
// ------------------------------------------------------------------
__global__ __launch_bounds__(512) void fc_mfma(
    const unsigned short* __restrict__ xcatb, const float* __restrict__ fcW,
    const float* __restrict__ fcb, float* __restrict__ pred)
{
    __shared__ unsigned short As[256 * 72];  // 36 KB
    __shared__ unsigned short Bs[64 * 72];   // 9 KB
    const int n0 = blockIdx.x * 64;
    const int tid = threadIdx.x, lane = tid & 63, wid = tid >> 6;
    const int wm = wid >> 1, wn = wid & 1;   // 4 x 2 waves: 64 rows x 32 cols each
    const int l15 = lane & 15, lk = lane >> 4;

    f32x4 acc[4][2] = {};
    for (int k0 = 0; k0 < KF; k0 += 64) {
        #pragma unroll
        for (int j = 0; j < 4; ++j) {        // A: 256 rows x 8 chunks, bf16 copy
            const int ci = tid + 512 * j;
            const int row = ci >> 3, kc = ci & 7;
            *reinterpret_cast<short8v*>(&As[row * 72 + kc * 8]) =
                *reinterpret_cast<const short8v*>(
                    &xcatb[(size_t)row * KF + k0 + kc * 8]);
        }
        {                                    // B: 64 rows x 8 chunks, f32->bf16
            const int row = tid >> 3, kc = tid & 7;
            const float* src = &fcW[(size_t)(n0 + row) * KF + k0 + kc * 8];
            const float4 f0 = *reinterpret_cast<const float4*>(src);
            const float4 f1 = *reinterpret_cast<const float4*>(src + 4);
            short8v t;
            t[0] = (short)f2bf(f0.x); t[1] = (short)f2bf(f0.y);
            t[2] = (short)f2bf(f0.z); t[3] = (short)f2bf(f0.w);
            t[4] = (short)f2bf(f1.x); t[5] = (short)f2bf(f1.y);
            t[6] = (short)f2bf(f1.z); t[7] = (short)f2bf(f1.w);
            *reinterpret_cast<short8v*>(&Bs[row * 72 + kc * 8]) = t;
        }
        __syncthreads();
        #pragma unroll
        for (int kk = 0; kk < 2; ++kk) {
            short8v bfr[2];
            #pragma unroll
            for (int nf = 0; nf < 2; ++nf)
                bfr[nf] = *reinterpret_cast<const short8v*>(
                    &Bs[(wn * 32 + nf * 16 + l15) * 72 + kk * 32 + lk * 8]);
            #pragma unroll
            for (int mf = 0; mf < 4; ++mf) {
                const short8v afr = *reinterpret_cast<const short8v*>(
                    &As[(wm * 64 + mf * 16 + l15) * 72 + kk * 32 + lk * 8]);
                acc[mf][0] = __builtin_amdgcn_mfma_f32_16x16x32_bf16(
                    afr, bfr[0], acc[mf][0], 0, 0, 0);
                acc[mf][1] = __builtin_amdgcn_mfma_f32_16x16x32_bf16(
                    afr, bfr[1], acc[mf][1], 0, 0, 0);
            }
        }
        __syncthreads();
    }
    #pragma unroll
    for (int mf = 0; mf < 4; ++mf) {
        const int grow0 = wm * 64 + mf * 16 + lk * 4;
        #pragma unroll
        for (int nf = 0; nf < 2; ++nf) {
            const int gcol = n0 + wn * 32 + nf * 16 + l15;
            const float bias = fcb[gcol];
            #pragma unroll
            for (int r = 0; r < 4; ++r)
                pred[(size_t)(grow0 + r) * V + gcol] = acc[mf][nf][r] + bias;
        }
    }
}

// ------------------------------------------------------------------
// small bf16 GEMM for gi/gh: C[256,N] = Abf[256,K] @ bf16(Wf[N,K])^T + bias
// BM=256, BN=64, BK=64, 256 thr (4 waves 2Mx2N).
// ------------------------------------------------------------------
__global__ __launch_bounds__(256) void gemm_bf16_small(
    const unsigned short* __restrict__ Abf, const float* __restrict__ Wf,
    const float* __restrict__ bias, float* __restrict__ C, int K, int ldc)
{
    __shared__ unsigned short As[256 * 72];  // 36 KB
    __shared__ unsigned short Bs[64 * 72];   // 9 KB
    const int n0 = blockIdx.x * 64;
    const int tid = threadIdx.x, lane = tid & 63, wid = tid >> 6;
    const int wm = wid >> 1, wn = wid & 1;   // 2 x 2 waves: 128 rows x 32 cols
    const int l15 = lane & 15, lk = lane >> 4;

    f32x4 acc[8][2] = {};
    for (int k0 = 0; k0 < K; k0 += 64) {
        #pragma unroll
        for (int j = 0; j < 8; ++j) {        // A: 2048 chunks
            const int ci = tid + 256 * j;
            const int row = ci >> 3, kc = ci & 7;
            *reinterpret_cast<short8v*>(&As[row * 72 + kc * 8]) =
                *reinterpret_cast<const short8v*>(
                    &Abf[(size_t)row * K + k0 + kc * 8]);
        }
        #pragma unroll
        for (int j = 0; j < 2; ++j) {        // B: 512 chunks, f32->bf16
            const int ci = tid + 256 * j;
            const int row = ci >> 3, kc = ci & 7;
            const float* src = &Wf[(size_t)(n0 + row) * K + k0 + kc * 8];
            const float4 f0 = *reinterpret_cast<const float4*>(src);
            const float4 f1 = *reinterpret_cast<const float4*>(src + 4);
            short8v t;
            t[0] = (short)f2bf(f0.x); t[1] = (short)f2bf(f0.y);
            t[2] = (short)f2bf(f0.z); t[3] = (short)f2bf(f0.w);
            t[4] = (short)f2bf(f1.x); t[5] = (short)f2bf(f1.y);
            t[6] = (short)f2bf(f1.z); t[7] = (short)f2bf(f1.w);
            *reinterpret_cast<short8v*>(&Bs[row * 72 + kc * 8]) = t;
        }
        __syncthreads();
        #pragma unroll
        for (int kk = 0; kk < 2; ++kk) {
            short8v bfr[2];
            #pragma unroll
            for (int nf = 0; nf < 2; ++nf)
                bfr[nf] = *reinterpret_cast<const short8v*>(
                    &Bs[(wn * 32 + nf * 16 + l15) * 72 + kk * 32 + lk * 8]);
            #pragma unroll
            for (int mf = 0; mf < 8; ++mf) {
                const short8v afr = *reinterpret_cast<const short8v*>(
                    &As[(wm * 128 + mf * 16 + l15) * 72 + kk * 32 + lk * 8]);
                acc[mf][0] = __builtin_amdgcn_mfma_f32_16x16x32_bf16(
                    afr, bfr[0], acc[mf][0], 0, 0, 0);
                acc[mf][1] = __builtin_amdgcn_mfma_f32_16x16x32_bf16(
                    afr, bfr[1], acc[mf][1], 0, 0, 0);
            }
        }
        __syncthreads();
    }
    #pragma unroll
    for (int mf = 0; mf < 8; ++mf) {
        const int grow0 = wm * 128 + mf * 16 + lk * 4;
        #pragma unroll
        for (int nf = 0; nf < 2; ++nf) {
            const int gcol = n0 + wn * 32 + nf * 16 + l15;
            const float bv = bias[gcol];
            #pragma unroll
            for (int r = 0; r < 4; ++r)
                C[(size_t)(grow0 + r) * ldc + gcol] = acc[mf][nf][r] + bv;
        }
    }
}

// ------------------------------------------------------------------
// softmax over s per b + weighted sum (from encb bf16); writes weighted
// into xcatb[:,512:1024] and xb[:,256:768] (both bf16).
// ------------------------------------------------------------------
__global__ __launch_bounds__(256) void softmax_weighted(
    const float* __restrict__ scores, const unsigned short* __restrict__ encb,
    unsigned short* __restrict__ xcatb, unsigned short* __restrict__ xb)
{
    const int b   = blockIdx.x;
    const int tid = threadIdx.x;
    __shared__ float sa[S];
    __shared__ float red[128];

    const float sc = (tid < S) ? scores[(size_t)tid * B + b] : -1e30f;
    if (tid < 128) red[tid] = sc;
    __syncthreads();
    for (int off = 64; off >= 1; off >>= 1) {
        if (tid < off) red[tid] = fmaxf(red[tid], red[tid + off]);
        __syncthreads();
    }
    const float mx = red[0];
    __syncthreads();
    const float e = (tid < S) ? expf(sc - mx) : 0.0f;
    if (tid < 128) red[tid] = e;
    __syncthreads();
    for (int off = 64; off >= 1; off >>= 1) {
        if (tid < off) red[tid] += red[tid + off];
        __syncthreads();
    }
    const float inv = 1.0f / red[0];
    __syncthreads();
    if (tid < S) sa[tid] = e * inv;
    __syncthreads();

    float acc0 = 0.0f, acc1 = 0.0f;
    const int e0 = tid * 2;
    for (int s = 0; s < S; ++s) {
        const float w = sa[s];
        const unsigned u = *reinterpret_cast<const unsigned*>(
            &encb[((size_t)s * B + b) * ENC + e0]);
        acc0 = fmaf(w, bf2f((unsigned short)(u & 0xffffu)), acc0);
        acc1 = fmaf(w, bf2f((unsigned short)(u >> 16)), acc1);
    }
    unsigned short t2[2] = { f2bf(acc0), f2bf(acc1) };
    const unsigned packed = *reinterpret_cast<unsigned*>(t2);
    *reinterpret_cast<unsigned*>(&xcatb[(size_t)b * KF + DEC + e0]) = packed;
    *reinterpret_cast<unsigned*>(&xb[(size_t)b * KX + EMB + e0])    = packed;
}

// emb gather -> xb[:,0:256] and xcatb[:,1024:1280] (bf16)
__global__ void gather_emb(const int* __restrict__ tok, const float* __restrict__ table,
                           unsigned short* __restrict__ xcatb, unsigned short* __restrict__ xb)
{
    const int b = blockIdx.x, t = threadIdx.x;  // 64 threads
    const float4 v4 = *reinterpret_cast<const float4*>(
        &table[(size_t)tok[b] * EMB + t * 4]);
    unsigned short o[4] = { f2bf(v4.x), f2bf(v4.y), f2bf(v4.z), f2bf(v4.w) };
    const uint2 p = *reinterpret_cast<uint2*>(o);
    *reinterpret_cast<uint2*>(&xcatb[(size_t)b * KF + DEC + ENC + t * 4]) = p;
    *reinterpret_cast<uint2*>(&xb[(size_t)b * KX + t * 4]) = p;
}

// GRU gates; h_new -> xcatb[:,0:512] (bf16) and d_out tail (f32)
__global__ __launch_bounds__(256) void gru_gates(
    const float* __restrict__ gi, const float* __restrict__ gh,
    const float* __restrict__ h, unsigned short* __restrict__ xcatb,
    float* __restrict__ h_out)
{
    const int idx = blockIdx.x * 256 + threadIdx.x;
    const int b = idx >> 9, d = idx & 511;
    const float* gib = gi + (size_t)b * G3;
    const float* ghb = gh + (size_t)b * G3;
    const float r  = sigmoidf(gib[d] + ghb[d]);
    const float z  = sigmoidf(gib[DEC + d] + ghb[DEC + d]);
    const float n  = tanhf(gib[2 * DEC + d] + r * ghb[2 * DEC + d]);
    const float hv = h[(size_t)b * DEC + d];
    const float hn = (1.0f - z) * n + z * hv;
    xcatb[(size_t)b * KF + d] = f2bf(hn);
    h_out[(size_t)b * DEC + d] = hn;
}

extern "C" void kernel_launch(void* const* d_in, const int* in_sizes, int n_in,
                              void* d_out, int out_size, void* d_ws, size_t ws_size,
                              hipStream_t stream)
{
    const int*   tok    = (const int*)d_in[0];
    const float* hidden = (const float*)d_in[1];
    const float* enc    = (const float*)d_in[2];
    const float* table  = (const float*)d_in[3];
    const float* attn_W = (const float*)d_in[4];
    const float* attn_b = (const float*)d_in[5];
    const float* vvec   = (const float*)d_in[6];
    const float* W_ih   = (const float*)d_in[7];
    const float* W_hh   = (const float*)d_in[8];
    const float* b_ih   = (const float*)d_in[9];
    const float* b_hh   = (const float*)d_in[10];
    const float* fc_W   = (const float*)d_in[11];
    const float* fc_b   = (const float*)d_in[12];

    float* ws     = (float*)d_ws;
    float* hWb    = ws;                       // 131072 f32
    float* scores = hWb + B * DEC;            //  32768 f32
    float* gi     = scores + S * B;           // 393216 f32
    float* gh     = gi + B * G3;              // 393216 f32
    unsigned short* xcatb = (unsigned short*)(gh + B * G3);     // B*KF
    unsigned short* WeT   = xcatb + (size_t)B * KF;             // 512*512
    unsigned short* xb    = WeT + (size_t)512 * 512;            // B*KX
    unsigned short* hb    = xb + (size_t)B * KX;                // B*DEC
    unsigned short* encb  = hb + (size_t)B * DEC;               // 32768*512
    // total ~39 MB

    float* pred  = (float*)d_out;
    float* h_out = pred + (size_t)B * V;

    hipMemsetAsync(scores, 0, (size_t)S * B * sizeof(float), stream);

    conv_enc<<<2048, 256, 0, stream>>>(enc, encb);
    conv_h<<<64, 256, 0, stream>>>(hidden, hb);
    transpose_We<<<dim3(16, 16), 256, 0, stream>>>(attn_W, WeT);
    gather_emb<<<B, 64, 0, stream>>>(tok, table, xcatb, xb);

    // hWb = h @ attn_W[0:DEC,:] + attn_b   (f32 for tanh-arg accuracy)
    gemm_f32<0, 1><<<dim3(DEC / 64, B / 64), 256, 0, stream>>>(
        hidden, attn_W, attn_b, hWb, B, DEC, DEC, DEC, DEC, DEC);

    energy_mfma<<<512, 512, 0, stream>>>(encb, WeT, hWb, vvec, scores);

    softmax_weighted<<<B, 256, 0, stream>>>(scores, encb, xcatb, xb);

    gemm_bf16_small<<<G3 / 64, 256, 0, stream>>>(xb, W_ih, b_ih, gi, KX, G3);
    gemm_bf16_small<<<G3 / 64, 256, 0, stream>>>(hb, W_hh, b_hh, gh, DEC, G3);

    gru_gates<<<(B * DEC) / 256, 256, 0, stream>>>(gi, gh, hidden, xcatb, h_out);

    fc_mfma<<<V / 64, 512, 0, stream>>>(xcatb, fc_W, fc_b, pred);
}

// Round 11
// 456.631 us; speedup vs baseline: 1.9607x; 1.0454x over previous
//
#include <hip/hip_runtime.h>
#include <cmath>

static constexpr int B   = 256;
static constexpr int S   = 128;
static constexpr int ENC = 512;
static constexpr int DEC = 512;
static constexpr int EMB = 256;
static constexpr int V   = 32000;
static constexpr int KX  = EMB + ENC;        // 768
static constexpr int KF  = DEC + ENC + EMB;  // 1280
static constexpr int G3  = 3 * DEC;          // 1536

typedef __attribute__((ext_vector_type(8))) short short8v;
typedef __attribute__((ext_vector_type(4))) float f32x4;

__device__ __forceinline__ float sigmoidf(float xv) { return 1.0f / (1.0f + expf(-xv)); }

__device__ __forceinline__ unsigned short f2bf(float f) {
    unsigned u = __float_as_uint(f);
    unsigned r = (u + 0x7fffu + ((u >> 16) & 1u)) >> 16;
    return (unsigned short)r;
}
__device__ __forceinline__ float bf2f(unsigned short s) {
    return __uint_as_float(((unsigned)s) << 16);
}

// ------------------------------------------------------------------
// f32 tiled GEMM — used only for hWb (small, f32 accuracy kept on tanh arg)
// ------------------------------------------------------------------
template<int TRANSB, int BIAS>
__global__ __launch_bounds__(256) void gemm_f32(
    const float* __restrict__ A, const float* __restrict__ Bm,
    const float* __restrict__ bias, float* __restrict__ C,
    int M, int N, int K, int lda, int ldb, int ldc)
{
    __shared__ float As[16][68];
    __shared__ float Bs[16][68];
    const int tid  = threadIdx.x;
    const int row0 = blockIdx.y * 64;
    const int col0 = blockIdx.x * 64;
    const int tx = tid & 15, ty = tid >> 4;

    float acc[4][4] = {};
    for (int k0 = 0; k0 < K; k0 += 16) {
        {
            const int m  = tid >> 2;
            const int kk = (tid & 3) << 2;
            const float4 a4 = *reinterpret_cast<const float4*>(
                &A[(size_t)(row0 + m) * lda + k0 + kk]);
            As[kk + 0][m] = a4.x; As[kk + 1][m] = a4.y;
            As[kk + 2][m] = a4.z; As[kk + 3][m] = a4.w;
        }
        if (TRANSB) {
            const int n  = tid >> 2;
            const int kk = (tid & 3) << 2;
            const float4 b4 = *reinterpret_cast<const float4*>(
                &Bm[(size_t)(col0 + n) * ldb + k0 + kk]);
            Bs[kk + 0][n] = b4.x; Bs[kk + 1][n] = b4.y;
            Bs[kk + 2][n] = b4.z; Bs[kk + 3][n] = b4.w;
        } else {
            const int kk = tid >> 4;
            const int n  = (tid & 15) << 2;
            *reinterpret_cast<float4*>(&Bs[kk][n]) =
                *reinterpret_cast<const float4*>(&Bm[(size_t)(k0 + kk) * ldb + col0 + n]);
        }
        __syncthreads();
        #pragma unroll
        for (int k = 0; k < 16; ++k) {
            float a4[4], b4[4];
            *reinterpret_cast<float4*>(a4) = *reinterpret_cast<const float4*>(&As[k][ty << 2]);
            *reinterpret_cast<float4*>(b4) = *reinterpret_cast<const float4*>(&Bs[k][tx << 2]);
            #pragma unroll
            for (int i = 0; i < 4; ++i)
                #pragma unroll
                for (int j = 0; j < 4; ++j)
                    acc[i][j] = fmaf(a4[i], b4[j], acc[i][j]);
        }
        __syncthreads();
    }
    #pragma unroll
    for (int i = 0; i < 4; ++i) {
        const int r = row0 + (ty << 2) + i;
        #pragma unroll
        for (int j = 0; j < 4; ++j) {
            const int c = col0 + (tx << 2) + j;
            float outv = acc[i][j];
            if (BIAS) outv += bias[c];
            C[(size_t)r * ldc + c] = outv;
        }
    }
}

// enc f32 -> bf16, exact cover: 2048 blocks x 256 thr x 8 elems x 4 iters
__global__ __launch_bounds__(256) void conv_enc(
    const float* __restrict__ src, unsigned short* __restrict__ dst)
{
    size_t base = ((size_t)blockIdx.x * 256 + threadIdx.x) * 8;
    const size_t stride = (size_t)2048 * 256 * 8;
    #pragma unroll
    for (int it = 0; it < 4; ++it, base += stride) {
        const float4 f0 = *reinterpret_cast<const float4*>(&src[base]);
        const float4 f1 = *reinterpret_cast<const float4*>(&src[base + 4]);
        short8v t;
        t[0] = (short)f2bf(f0.x); t[1] = (short)f2bf(f0.y);
        t[2] = (short)f2bf(f0.z); t[3] = (short)f2bf(f0.w);
        t[4] = (short)f2bf(f1.x); t[5] = (short)f2bf(f1.y);
        t[6] = (short)f2bf(f1.z); t[7] = (short)f2bf(f1.w);
        *reinterpret_cast<short8v*>(&dst[base]) = t;
    }
}

// hidden f32 -> bf16 (131072 elems = 64 blocks x 256 thr x 8)
__global__ __launch_bounds__(256) void conv_h(
    const float* __restrict__ src, unsigned short* __restrict__ dst)
{
    const size_t base = ((size_t)blockIdx.x * 256 + threadIdx.x) * 8;
    const float4 f0 = *reinterpret_cast<const float4*>(&src[base]);
    const float4 f1 = *reinterpret_cast<const float4*>(&src[base + 4]);
    short8v t;
    t[0] = (short)f2bf(f0.x); t[1] = (short)f2bf(f0.y);
    t[2] = (short)f2bf(f0.z); t[3] = (short)f2bf(f0.w);
    t[4] = (short)f2bf(f1.x); t[5] = (short)f2bf(f1.y);
    t[6] = (short)f2bf(f1.z); t[7] = (short)f2bf(f1.w);
    *reinterpret_cast<short8v*>(&dst[base]) = t;
}

// attn_W enc-half [k=512][n=512] f32 -> WeT [n][k] bf16
__global__ __launch_bounds__(256) void transpose_We(
    const float* __restrict__ attn_W, unsigned short* __restrict__ WeT)
{
    __shared__ float t[32][33];
    const int k0 = blockIdx.x * 32, n0 = blockIdx.y * 32;
    const int r = threadIdx.x >> 3, c4 = (threadIdx.x & 7) * 4;
    const float4 f = *reinterpret_cast<const float4*>(
        &attn_W[(size_t)(DEC + k0 + r) * DEC + n0 + c4]);
    t[r][c4] = f.x; t[r][c4 + 1] = f.y; t[r][c4 + 2] = f.z; t[r][c4 + 3] = f.w;
    __syncthreads();
    unsigned short o[4] = { f2bf(t[c4 + 0][r]), f2bf(t[c4 + 1][r]),
                            f2bf(t[c4 + 2][r]), f2bf(t[c4 + 3][r]) };
    *reinterpret_cast<uint2*>(&WeT[(size_t)(n0 + r) * 512 + k0 + c4]) =
        *reinterpret_cast<uint2*>(o);
}

// ------------------------------------------------------------------
// energy v2: C[32768,512] = encb @ WeT^T; epilogue v.tanh(C+hWb) -> scores.
// BM=128, BN=256, BK=64, 512 thr (8 waves 2Mx4N), grid 512 (2 blocks/CU).
// ------------------------------------------------------------------
__global__ __launch_bounds__(512, 4) void energy_mfma(
    const unsigned short* __restrict__ encb, const unsigned short* __restrict__ WeT,
    const float* __restrict__ hWb, const float* __restrict__ vvec,
    float* __restrict__ scores)
{
    __shared__ unsigned short Ae[128 * 72];  // 18 KB
    __shared__ unsigned short Be[256 * 72];  // 36 KB
    const int bid = blockIdx.x;                        // 512 blocks
    const int logical = (bid & 7) * 64 + (bid >> 3);   // bijective, 512%8==0
    const int mb = logical >> 1, nb = logical & 1;
    const int tid = threadIdx.x, lane = tid & 63, wid = tid >> 6;
    const int wm = wid >> 2, wn = wid & 3;             // 2 x 4 waves
    const int l15 = lane & 15, lk = lane >> 4;

    f32x4 acc[4][4] = {};
    for (int k0 = 0; k0 < 512; k0 += 64) {
        #pragma unroll
        for (int j = 0; j < 2; ++j) {          // A: 128 rows x 8 chunks
            const int ci = tid + 512 * j;
            const int row = ci >> 3, kc = ci & 7;
            *reinterpret_cast<short8v*>(&Ae[row * 72 + kc * 8]) =
                *reinterpret_cast<const short8v*>(
                    &encb[(size_t)(mb * 128 + row) * 512 + k0 + kc * 8]);
        }
        #pragma unroll
        for (int j = 0; j < 4; ++j) {          // B: 256 rows x 8 chunks
            const int ci = tid + 512 * j;
            const int row = ci >> 3, kc = ci & 7;
            *reinterpret_cast<short8v*>(&Be[row * 72 + kc * 8]) =
                *reinterpret_cast<const short8v*>(
                    &WeT[(size_t)(nb * 256 + row) * 512 + k0 + kc * 8]);
        }
        __syncthreads();
        #pragma unroll
        for (int kk = 0; kk < 2; ++kk) {
            short8v bfr[4];
            #pragma unroll
            for (int nf = 0; nf < 4; ++nf)
                bfr[nf] = *reinterpret_cast<const short8v*>(
                    &Be[(wn * 64 + nf * 16 + l15) * 72 + kk * 32 + lk * 8]);
            #pragma unroll
            for (int mf = 0; mf < 4; ++mf) {
                const short8v afr = *reinterpret_cast<const short8v*>(
                    &Ae[(wm * 64 + mf * 16 + l15) * 72 + kk * 32 + lk * 8]);
                #pragma unroll
                for (int nf = 0; nf < 4; ++nf)
                    acc[mf][nf] = __builtin_amdgcn_mfma_f32_16x16x32_bf16(
                        afr, bfr[nf], acc[mf][nf], 0, 0, 0);
            }
        }
        __syncthreads();
    }
    const int colbase = nb * 256 + wn * 64;
    #pragma unroll
    for (int mf = 0; mf < 4; ++mf) {
        #pragma unroll
        for (int r = 0; r < 4; ++r) {
            const int rl = wm * 64 + mf * 16 + lk * 4 + r;
            const int g  = mb * 128 + rl;       // global row = s*B + b
            const int b  = g & (B - 1);
            float p = 0.0f;
            #pragma unroll
            for (int nf = 0; nf < 4; ++nf) {
                const int col = colbase + nf * 16 + l15;
                p += vvec[col] * tanhf(acc[mf][nf][r] + hWb[(size_t)b * DEC + col]);
            }
            p += __shfl_xor(p, 1, 64);
            p += __shfl_xor(p, 2, 64);
            p += __shfl_xor(p, 4, 64);
            p += __shfl_xor(p, 8, 64);
            if (l15 == 0) atomicAdd(&scores[g], p);
        }
    }
}

// ------------------------------------------------------------------
// fc v4: pred[256,32000] = xcatb @ bf16(fc_W)^T + fc_b.
// BM=256, BN=64, BK=64, 512 thr (8 waves 4Mx2N), grid 500, 45KB LDS
// (2 blocks/CU). NEW: async-STAGE reg-prefetch — tile t+1's global loads
// are issued BEFORE tile t's MFMA so HBM/L3 latency hides under compute
// + barrier instead of being serially drained each K-step (round-9/10
// counters: all pipes <20% busy => latency-bound duty-cycle problem).
// ------------------------------------------------------------------
__global__ __launch_bounds__(512) void fc_mfma(
    const unsigned short* __restrict__ xcatb, const float* __restrict__ fcW,
    const float* __restrict__ fcb, float* __restrict__ pred)
{
    __shared__ unsigned short As[256 * 72];  // 36 KB
    __shared__ unsigned short Bs[64 * 72];   // 9 KB
    const int n0 = blockIdx.x * 64;
    const int tid = threadIdx.x, lane = tid & 63, wid = tid >> 6;
    const int wm = wid >> 1, wn = wid & 1;   // 4 x 2 waves: 64 rows x 32 cols
    const int l15 = lane & 15, lk = lane >> 4;
    const int brow = tid >> 3, bkc = tid & 7;

    short8v aReg[4];
    float4  bR0, bR1;

    // prologue: tile 0 -> regs
    #pragma unroll
    for (int j = 0; j < 4; ++j) {
        const int ci = tid + 512 * j;
        const int row = ci >> 3, kc = ci & 7;
        aReg[j] = *reinterpret_cast<const short8v*>(
            &xcatb[(size_t)row * KF + kc * 8]);
    }
    {
        const float* src = &fcW[(size_t)(n0 + brow) * KF + bkc * 8];
        bR0 = *reinterpret_cast<const float4*>(src);
        bR1 = *reinterpret_cast<const float4*>(src + 4);
    }

    f32x4 acc[4][2] = {};
    for (int t = 0; t < KF / 64; ++t) {
        __syncthreads();                     // prev compute done; LDS writable
        #pragma unroll
        for (int j = 0; j < 4; ++j) {        // A: regs -> LDS
            const int ci = tid + 512 * j;
            const int row = ci >> 3, kc = ci & 7;
            *reinterpret_cast<short8v*>(&As[row * 72 + kc * 8]) = aReg[j];
        }
        {                                    // B: convert + store
            short8v tB;
            tB[0] = (short)f2bf(bR0.x); tB[1] = (short)f2bf(bR0.y);
            tB[2] = (short)f2bf(bR0.z); tB[3] = (short)f2bf(bR0.w);
            tB[4] = (short)f2bf(bR1.x); tB[5] = (short)f2bf(bR1.y);
            tB[6] = (short)f2bf(bR1.z); tB[7] = (short)f2bf(bR1.w);
            *reinterpret_cast<short8v*>(&Bs[brow * 72 + bkc * 8]) = tB;
        }
        if (t + 1 < KF / 64) {               // issue t+1 loads (fly during MFMA)
            const int k0 = (t + 1) * 64;
            #pragma unroll
            for (int j = 0; j < 4; ++j) {
                const int ci = tid + 512 * j;
                const int row = ci >> 3, kc = ci & 7;
                aReg[j] = *reinterpret_cast<const short8v*>(
                    &xcatb[(size_t)row * KF + k0 + kc * 8]);
            }
            const float* src = &fcW[(size_t)(n0 + brow) * KF + k0 + bkc * 8];
            bR0 = *reinterpret_cast<const float4*>(src);
            bR1 = *reinterpret_cast<const float4*>(src + 4);
        }
        __syncthreads();                     // LDS tile t visible
        #pragma unroll
        for (int kk = 0; kk < 2; ++kk) {
            short8v bfr[2];
            #pragma unroll
            for (int nf = 0; nf < 2; ++nf)
                bfr[nf] = *reinterpret_cast<const short8v*>(
                    &Bs[(wn * 32 + nf * 16 + l15) * 72 + kk * 32 + lk * 8]);
            #pragma unroll
            for (int mf = 0; mf < 4; ++mf) {
                const short8v afr = *reinterpret_cast<const short8v*>(
                    &As[(wm * 64 + mf * 16 + l15) * 72 + kk * 32 + lk * 8]);
                acc[mf][0] = __builtin_amdgcn_mfma_f32_16x16x32_bf16(
                    afr, bfr[0], acc[mf][0], 0, 0, 0);
                acc[mf][1] = __builtin_amdgcn_mfma_f32_16x16x32_bf16(
                    afr, bfr[1], acc[mf][1], 0, 0, 0);
            }
        }
    }
    #pragma unroll
    for (int mf = 0; mf < 4; ++mf) {
        const int grow0 = wm * 64 + mf * 16 + lk * 4;
        #pragma unroll
        for (int nf = 0; nf < 2; ++nf) {
            const int gcol = n0 + wn * 32 + nf * 16 + l15;
            const float bias = fcb[gcol];
            #pragma unroll
            for (int r = 0; r < 4; ++r)
                pred[(size_t)(grow0 + r) * V + gcol] = acc[mf][nf][r] + bias;
        }
    }
}

// ------------------------------------------------------------------
// gi + gh in ONE launch (grid 48): blocks [0,24) -> gi = xb@W_ih^T+b_ih,
// blocks [24,48) -> gh = hb@W_hh^T+b_hh. Both BM=256, BN=64, BK=64,
// 256 thr (4 waves 2Mx2N). Was two serialized 24-block launches.
// ------------------------------------------------------------------
__global__ __launch_bounds__(256) void gru_gemms(
    const unsigned short* __restrict__ xb, const float* __restrict__ W_ih,
    const float* __restrict__ b_ih, float* __restrict__ gi,
    const unsigned short* __restrict__ hb, const float* __restrict__ W_hh,
    const float* __restrict__ b_hh, float* __restrict__ gh)
{
    const bool second = blockIdx.x >= (G3 / 64);
    const unsigned short* Abf = second ? hb : xb;
    const float* Wf   = second ? W_hh : W_ih;
    const float* bias = second ? b_hh : b_ih;
    float* C          = second ? gh : gi;
    const int K       = second ? DEC : KX;
    const int n0 = (second ? blockIdx.x - G3 / 64 : blockIdx.x) * 64;

    __shared__ unsigned short As[256 * 72];  // 36 KB
    __shared__ unsigned short Bs[64 * 72];   // 9 KB
    const int tid = threadIdx.x, lane = tid & 63, wid = tid >> 6;
    const int wm = wid >> 1, wn = wid & 1;
    const int l15 = lane & 15, lk = lane >> 4;

    f32x4 acc[8][2] = {};
    for (int k0 = 0; k0 < K; k0 += 64) {
        #pragma unroll
        for (int j = 0; j < 8; ++j) {
            const int ci = tid + 256 * j;
            const int row = ci >> 3, kc = ci & 7;
            *reinterpret_cast<short8v*>(&As[row * 72 + kc * 8]) =
                *reinterpret_cast<const short8v*>(
                    &Abf[(size_t)row * K + k0 + kc * 8]);
        }
        #pragma unroll
        for (int j = 0; j < 2; ++j) {
            const int ci = tid + 256 * j;
            const int row = ci >> 3, kc = ci & 7;
            const float* src = &Wf[(size_t)(n0 + row) * K + k0 + kc * 8];
            const float4 f0 = *reinterpret_cast<const float4*>(src);
            const float4 f1 = *reinterpret_cast<const float4*>(src + 4);
            short8v t;
            t[0] = (short)f2bf(f0.x); t[1] = (short)f2bf(f0.y);
            t[2] = (short)f2bf(f0.z); t[3] = (short)f2bf(f0.w);
            t[4] = (short)f2bf(f1.x); t[5] = (short)f2bf(f1.y);
            t[6] = (short)f2bf(f1.z); t[7] = (short)f2bf(f1.w);
            *reinterpret_cast<short8v*>(&Bs[row * 72 + kc * 8]) = t;
        }
        __syncthreads();
        #pragma unroll
        for (int kk = 0; kk < 2; ++kk) {
            short8v bfr[2];
            #pragma unroll
            for (int nf = 0; nf < 2; ++nf)
                bfr[nf] = *reinterpret_cast<const short8v*>(
                    &Bs[(wn * 32 + nf * 16 + l15) * 72 + kk * 32 + lk * 8]);
            #pragma unroll
            for (int mf = 0; mf < 8; ++mf) {
                const short8v afr = *reinterpret_cast<const short8v*>(
                    &As[(wm * 128 + mf * 16 + l15) * 72 + kk * 32 + lk * 8]);
                acc[mf][0] = __builtin_amdgcn_mfma_f32_16x16x32_bf16(
                    afr, bfr[0], acc[mf][0], 0, 0, 0);
                acc[mf][1] = __builtin_amdgcn_mfma_f32_16x16x32_bf16(
                    afr, bfr[1], acc[mf][1], 0, 0, 0);
            }
        }
        __syncthreads();
    }
    #pragma unroll
    for (int mf = 0; mf < 8; ++mf) {
        const int grow0 = wm * 128 + mf * 16 + lk * 4;
        #pragma unroll
        for (int nf = 0; nf < 2; ++nf) {
            const int gcol = n0 + wn * 32 + nf * 16 + l15;
            const float bv = bias[gcol];
            #pragma unroll
            for (int r = 0; r < 4; ++r)
                C[(size_t)(grow0 + r) * G3 + gcol] = acc[mf][nf][r] + bv;
        }
    }
}

// ------------------------------------------------------------------
// softmax over s per b + weighted sum (from encb bf16); writes weighted
// into xcatb[:,512:1024] and xb[:,256:768] (both bf16).
// ------------------------------------------------------------------
__global__ __launch_bounds__(256) void softmax_weighted(
    const float* __restrict__ scores, const unsigned short* __restrict__ encb,
    unsigned short* __restrict__ xcatb, unsigned short* __restrict__ xb)
{
    const int b   = blockIdx.x;
    const int tid = threadIdx.x;
    __shared__ float sa[S];
    __shared__ float red[128];

    const float sc = (tid < S) ? scores[(size_t)tid * B + b] : -1e30f;
    if (tid < 128) red[tid] = sc;
    __syncthreads();
    for (int off = 64; off >= 1; off >>= 1) {
        if (tid < off) red[tid] = fmaxf(red[tid], red[tid + off]);
        __syncthreads();
    }
    const float mx = red[0];
    __syncthreads();
    const float e = (tid < S) ? expf(sc - mx) : 0.0f;
    if (tid < 128) red[tid] = e;
    __syncthreads();
    for (int off = 64; off >= 1; off >>= 1) {
        if (tid < off) red[tid] += red[tid + off];
        __syncthreads();
    }
    const float inv = 1.0f / red[0];
    __syncthreads();
    if (tid < S) sa[tid] = e * inv;
    __syncthreads();

    float acc0 = 0.0f, acc1 = 0.0f;
    const int e0 = tid * 2;
    #pragma unroll 8
    for (int s = 0; s < S; ++s) {
        const float w = sa[s];
        const unsigned u = *reinterpret_cast<const unsigned*>(
            &encb[((size_t)s * B + b) * ENC + e0]);
        acc0 = fmaf(w, bf2f((unsigned short)(u & 0xffffu)), acc0);
        acc1 = fmaf(w, bf2f((unsigned short)(u >> 16)), acc1);
    }
    unsigned short t2[2] = { f2bf(acc0), f2bf(acc1) };
    const unsigned packed = *reinterpret_cast<unsigned*>(t2);
    *reinterpret_cast<unsigned*>(&xcatb[(size_t)b * KF + DEC + e0]) = packed;
    *reinterpret_cast<unsigned*>(&xb[(size_t)b * KX + EMB + e0])    = packed;
}

// emb gather -> xb[:,0:256] and xcatb[:,1024:1280] (bf16)
__global__ void gather_emb(const int* __restrict__ tok, const float* __restrict__ table,
                           unsigned short* __restrict__ xcatb, unsigned short* __restrict__ xb)
{
    const int b = blockIdx.x, t = threadIdx.x;  // 64 threads
    const float4 v4 = *reinterpret_cast<const float4*>(
        &table[(size_t)tok[b] * EMB + t * 4]);
    unsigned short o[4] = { f2bf(v4.x), f2bf(v4.y), f2bf(v4.z), f2bf(v4.w) };
    const uint2 p = *reinterpret_cast<uint2*>(o);
    *reinterpret_cast<uint2*>(&xcatb[(size_t)b * KF + DEC + ENC + t * 4]) = p;
    *reinterpret_cast<uint2*>(&xb[(size_t)b * KX + t * 4]) = p;
}

// GRU gates; h_new -> xcatb[:,0:512] (bf16) and d_out tail (f32)
__global__ __launch_bounds__(256) void gru_gates(
    const float* __restrict__ gi, const float* __restrict__ gh,
    const float* __restrict__ h, unsigned short* __restrict__ xcatb,
    float* __restrict__ h_out)
{
    const int idx = blockIdx.x * 256 + threadIdx.x;
    const int b = idx >> 9, d = idx & 511;
    const float* gib = gi + (size_t)b * G3;
    const float* ghb = gh + (size_t)b * G3;
    const float r  = sigmoidf(gib[d] + ghb[d]);
    const float z  = sigmoidf(gib[DEC + d] + ghb[DEC + d]);
    const float n  = tanhf(gib[2 * DEC + d] + r * ghb[2 * DEC + d]);
    const float hv = h[(size_t)b * DEC + d];
    const float hn = (1.0f - z) * n + z * hv;
    xcatb[(size_t)b * KF + d] = f2bf(hn);
    h_out[(size_t)b * DEC + d] = hn;
}

extern "C" void kernel_launch(void* const* d_in, const int* in_sizes, int n_in,
                              void* d_out, int out_size, void* d_ws, size_t ws_size,
                              hipStream_t stream)
{
    const int*   tok    = (const int*)d_in[0];
    const float* hidden = (const float*)d_in[1];
    const float* enc    = (const float*)d_in[2];
    const float* table  = (const float*)d_in[3];
    const float* attn_W = (const float*)d_in[4];
    const float* attn_b = (const float*)d_in[5];
    const float* vvec   = (const float*)d_in[6];
    const float* W_ih   = (const float*)d_in[7];
    const float* W_hh   = (const float*)d_in[8];
    const float* b_ih   = (const float*)d_in[9];
    const float* b_hh   = (const float*)d_in[10];
    const float* fc_W   = (const float*)d_in[11];
    const float* fc_b   = (const float*)d_in[12];

    float* ws     = (float*)d_ws;
    float* hWb    = ws;                       // 131072 f32
    float* scores = hWb + B * DEC;            //  32768 f32
    float* gi     = scores + S * B;           // 393216 f32
    float* gh     = gi + B * G3;              // 393216 f32
    unsigned short* xcatb = (unsigned short*)(gh + B * G3);     // B*KF
    unsigned short* WeT   = xcatb + (size_t)B * KF;             // 512*512
    unsigned short* xb    = WeT + (size_t)512 * 512;            // B*KX
    unsigned short* hb    = xb + (size_t)B * KX;                // B*DEC
    unsigned short* encb  = hb + (size_t)B * DEC;               // 32768*512
    // total ~39 MB

    float* pred  = (float*)d_out;
    float* h_out = pred + (size_t)B * V;

    hipMemsetAsync(scores, 0, (size_t)S * B * sizeof(float), stream);

    conv_enc<<<2048, 256, 0, stream>>>(enc, encb);
    conv_h<<<64, 256, 0, stream>>>(hidden, hb);
    transpose_We<<<dim3(16, 16), 256, 0, stream>>>(attn_W, WeT);
    gather_emb<<<B, 64, 0, stream>>>(tok, table, xcatb, xb);

    // hWb = h @ attn_W[0:DEC,:] + attn_b   (f32 for tanh-arg accuracy)
    gemm_f32<0, 1><<<dim3(DEC / 64, B / 64), 256, 0, stream>>>(
        hidden, attn_W, attn_b, hWb, B, DEC, DEC, DEC, DEC, DEC);

    energy_mfma<<<512, 512, 0, stream>>>(encb, WeT, hWb, vvec, scores);

    softmax_weighted<<<B, 256, 0, stream>>>(scores, encb, xcatb, xb);

    gru_gemms<<<2 * (G3 / 64), 256, 0, stream>>>(xb, W_ih, b_ih, gi,
                                                 hb, W_hh, b_hh, gh);

    gru_gates<<<(B * DEC) / 256, 256, 0, stream>>>(gi, gh, hidden, xcatb, h_out);

    fc_mfma<<<V / 64, 512, 0, stream>>>(xcatb, fc_W, fc_b, pred);
}